// Round 9
// baseline (2889.643 us; speedup 1.0000x reference)
//
#include <hip/hip_runtime.h>
#include <math.h>

#define TT     4000
#define DENC   1024
#define HD     1024
#define DEMB   512
#define VD     8193
#define NPH    800
#define BLANK  8192
#define NWG    256
#define NTHR   512
#define CHUNK_M 800
#define NSTEP  (NPH + 2)   // 802 sequential LSTM steps
#define NSTEPP 802
#define NVT    65          // v-tiles of 128
#define NP     129         // v-blocks of 64 (mfma partials per row)
#define CHUNK  256         // f32 fallback chunk

typedef __bf16 bf16x4 __attribute__((ext_vector_type(4)));
typedef __bf16 bf16x8 __attribute__((ext_vector_type(8)));
typedef float  f32x16 __attribute__((ext_vector_type(16)));
typedef unsigned long long u64t;

// ---- workspace layout (float offsets), mfma path (R4/R5-proven) ----
#define MEMSET_BYTES 20480
#define WSF_HX     1024                          // u64[2][512] packed {tag16|bf16}x2 exchange
#define WSF_HHIST  5120                          // NSTEP x 1024 f32
#define WSF_PREDS  826368                        // 801 x 1024 f32
#define WSF_GXT    826368                        // ALIAS: gxT[4096][802] f32 (dead after chain)
#define WSF_PMAX   1646592                       // TT*NP
#define WSF_PSUM   2162592
#define WSF_PARG   2678592
#define WSF_LSE    3194592
#define WSF_AMAX   3198592                       // 1024 ints
#define WSF_XBF    3199616                       // bf16 3328x1024
#define WSF_W16    4903552                       // bf16 8320x1024
#define WSF_END    9163392
#define NEED_MFMA  ((size_t)WSF_END * 4)
#define TST_IDX    512

// legacy f32-fallback layout (round-3/4, proven)
#define L_HX     1024
#define L_HHIST  5120
#define L_PREDS  826368
#define F_PMAX 1646592
#define F_PSUM 1906592
#define F_PARG 2166592
#define F_LSE  2426592

// ---- LDS sizes ----
#define GEMM_SMEM  12800                         // f32 tile: Wt[16][132]+Xt[16][68]
#define CHAIN_SMEM ((16 * NSTEPP + 2048 + 64) * 4)   // gxl f32 + h dbuf + GS
#define JOIN_SMEM  (65536 + 128)
// f32 fallback LDS layout (floats)
#define S_XH   0
#define S_GS   3072
#define S_C4   3088
#define S_TOK  3264
#define S_RED  4066
#define S_AMAX 4082
#define SMEM_FLOATS_F32 4352
#define SMEM_BYTES_F32 (SMEM_FLOATS_F32 * 4)

// ======================= shared helpers =======================

__device__ __forceinline__ float dot4(float4 a, float4 b, float acc) {
  acc = fmaf(a.x, b.x, acc); acc = fmaf(a.y, b.y, acc);
  acc = fmaf(a.z, b.z, acc); acc = fmaf(a.w, b.w, acc);
  return acc;
}
__device__ __forceinline__ float sigmf(float x) { return 1.f / (1.f + expf(-x)); }
__device__ __forceinline__ float sigm_fast(float x) { return 1.f / (1.f + __expf(-x)); }
__device__ __forceinline__ float tanh_fast(float x) {
  float e = __expf(2.f * x);
  return 1.f - 2.f / (e + 1.f);
}
__device__ __forceinline__ float bfbits_to_f32(unsigned u16v) {
  return __builtin_bit_cast(float, (u16v & 0xFFFFu) << 16);
}

__device__ __forceinline__ void combine3(float& m, float& s, int& am,
                                         float om, float os, int oa) {
  float mm = fmaxf(m, om);
  s = s * __expf(m - mm) + os * __expf(om - mm);
  if (om > m || (om == m && oa < am)) am = oa;
  m = mm;
}

__device__ __forceinline__ void gload16(const void* g, void* l) {
  __builtin_amdgcn_global_load_lds(
      (const __attribute__((address_space(1))) unsigned int*)g,
      (__attribute__((address_space(3))) unsigned int*)l, 16, 0, 0);
}

__device__ __forceinline__ float ld_coh(const float* p) {
  return __hip_atomic_load((const float*)p, __ATOMIC_RELAXED, __HIP_MEMORY_SCOPE_AGENT);
}

// light barrier: flag-array + release word (data must travel via sc1 atomics)
__device__ __forceinline__ void light_barrier(unsigned* flags, unsigned& ep) {
  unsigned* arrive  = flags;
  unsigned* release = flags + 256;
  __builtin_amdgcn_s_waitcnt(0);
  __syncthreads();
  if (blockIdx.x == 0) {
    int tid = threadIdx.x;
    if (tid > 0 && tid < NWG) {
      while (__hip_atomic_load(&arrive[tid], __ATOMIC_RELAXED, __HIP_MEMORY_SCOPE_AGENT) != ep) {}
    }
    __syncthreads();
    if (tid == 0)
      __hip_atomic_store(release, ep, __ATOMIC_RELAXED, __HIP_MEMORY_SCOPE_AGENT);
  } else {
    if (threadIdx.x == 0) {
      __hip_atomic_store(&arrive[blockIdx.x], ep, __ATOMIC_RELAXED, __HIP_MEMORY_SCOPE_AGENT);
      while (__hip_atomic_load(release, __ATOMIC_RELAXED, __HIP_MEMORY_SCOPE_AGENT) != ep) {}
    }
    __syncthreads();
  }
  asm volatile("" ::: "memory");
  ep++;
}

// heavy barrier: full fence (wbl2+inv) for plain-store handoffs
__device__ __forceinline__ void heavy_barrier(unsigned* flags) {
  unsigned* bar = flags + 257;
  __syncthreads();
  if (threadIdx.x == 0) {
    __threadfence();
    unsigned g = __hip_atomic_load(&bar[1], __ATOMIC_RELAXED, __HIP_MEMORY_SCOPE_AGENT);
    unsigned v = __hip_atomic_fetch_add(&bar[0], 1u, __ATOMIC_RELAXED, __HIP_MEMORY_SCOPE_AGENT);
    if (v == (unsigned)(NWG - 1)) {
      __hip_atomic_store(&bar[0], 0u, __ATOMIC_RELAXED, __HIP_MEMORY_SCOPE_AGENT);
      __hip_atomic_store(&bar[1], g + 1u, __ATOMIC_RELEASE, __HIP_MEMORY_SCOPE_AGENT);
    } else {
      while (__hip_atomic_load(&bar[1], __ATOMIC_RELAXED, __HIP_MEMORY_SCOPE_AGENT) == g)
        __builtin_amdgcn_s_sleep(1);
    }
    __threadfence();
  }
  __syncthreads();
}

// Xbf rows: dst[j] = bf16(relu(enc[t0+j] + preds[pi])), j in [0,K)
__device__ void xbf_fill(const float* enc, const float* preds, __bf16* dst,
                         int t0, int K, int pi0, int g0, int gs) {
  int total = K << 8;
  for (int q = g0; q < total; q += gs) {
    int j = q >> 8, seg = q & 255;
    int pi = (pi0 < 0) ? NPH : pi0 + j;
    float4 e = ((const float4*)(enc + (size_t)(t0 + j) * 1024))[seg];
    float4 p = ((const float4*)(preds + (size_t)pi * 1024))[seg];
    bf16x4 r;
    r[0] = (__bf16)fmaxf(e.x + p.x, 0.f);
    r[1] = (__bf16)fmaxf(e.y + p.y, 0.f);
    r[2] = (__bf16)fmaxf(e.z + p.z, 0.f);
    r[3] = (__bf16)fmaxf(e.w + p.w, 0.f);
    *(bf16x4*)(dst + (size_t)j * 1024 + (seg << 2)) = r;
  }
}

// MFMA joiner: 128v x 128j tiles, 8 waves, mfma_f32_32x32x16_bf16, fused partials
__device__ void joiner_tiles(const __bf16* W16, const __bf16* xrows, const float* bj,
                             float* out_align, float* pmax, float* psum, int* parg,
                             char* smc, int t0, int K, int tile0, int tstride) {
  const int tid = threadIdx.x;
  const int wid = tid >> 6, lane = tid & 63;
  const int wj = wid & 3, wv = wid >> 2;
  const int l31 = lane & 31, lhi = lane >> 5;
  const int jt_n = (K + 127) >> 7;
  const int ntiles = jt_n * NVT;

  for (int tile = tile0; tile < ntiles; tile += tstride) {
    const int vt = tile % NVT, jt = tile / NVT;
    const int v0 = vt << 7, j0 = jt << 7;
    f32x16 acc0, acc1;
    #pragma unroll
    for (int i = 0; i < 16; ++i) { acc0[i] = 0.f; acc1[i] = 0.f; }

    auto stage = [&](int db, int kb) {
      char* wb = smc + db * 32768;
      char* xb = wb + 16384;
      #pragma unroll
      for (int p = 0; p < 2; ++p) {
        int sbase = p * 512 + wid * 64;
        int s = sbase + lane;
        int ks = s >> 7, r = s & 127;
        gload16(W16 + (size_t)(v0 + r) * 1024 + kb + ks * 8, wb + sbase * 16);
        gload16(xrows + (size_t)(j0 + r) * 1024 + kb + ks * 8, xb + sbase * 16);
      }
    };

    stage(0, 0);
    __syncthreads();
    int db = 0;
    for (int kb16 = 0; kb16 < 16; ++kb16) {
      if (kb16 < 15) stage(db ^ 1, (kb16 + 1) << 6);
      const char* wb = smc + db * 32768;
      const char* xb = wb + 16384;
      #pragma unroll
      for (int k16 = 0; k16 < 4; ++k16) {
        int ks = k16 * 2 + lhi;
        bf16x8 a  = *(const bf16x8*)(xb + ((ks << 7) + (wj << 5) + l31) * 16);
        bf16x8 b0 = *(const bf16x8*)(wb + ((ks << 7) + (wv << 6) + l31) * 16);
        bf16x8 b1 = *(const bf16x8*)(wb + ((ks << 7) + (wv << 6) + 32 + l31) * 16);
        acc0 = __builtin_amdgcn_mfma_f32_32x32x16_bf16(a, b0, acc0, 0, 0, 0);
        acc1 = __builtin_amdgcn_mfma_f32_32x32x16_bf16(a, b1, acc1, 0, 0, 0);
      }
      __syncthreads();
      db ^= 1;
    }

    const int v_0 = v0 + (wv << 6) + l31;
    const int v_1 = v_0 + 32;
    const float bj0 = (v_0 < VD) ? bj[v_0] : 0.f;
    const float bj1 = (v_1 < VD) ? bj[v_1] : 0.f;
    const int jbase = j0 + (wj << 5) + 4 * lhi;
    const bool npok = (v0 + (wv << 6)) < VD;
    const int np = (v0 >> 6) + wv;
    #pragma unroll
    for (int reg = 0; reg < 16; ++reg) {
      int j = jbase + (reg & 3) + 8 * (reg >> 2);
      bool jok = j < K;
      float lg0 = acc0[reg] + bj0;
      float lg1 = acc1[reg] + bj1;
      if (jok) {
        size_t ro = (size_t)(t0 + j) * VD;
        if (v_0 < VD) out_align[ro + v_0] = lg0;
        if (v_1 < VD) out_align[ro + v_1] = lg1;
      }
      float l0 = (v_0 < VD) ? lg0 : -1e30f;
      float l1 = (v_1 < VD) ? lg1 : -1e30f;
      float m = fmaxf(l0, l1);
      float ss = 0.f;
      if (v_0 < VD) ss += __expf(l0 - m);
      if (v_1 < VD) ss += __expf(l1 - m);
      int am = (l1 > l0) ? v_1 : v_0;
      #pragma unroll
      for (int msk = 1; msk <= 16; msk <<= 1) {
        float om = __shfl_xor(m, msk, 64);
        float os = __shfl_xor(ss, msk, 64);
        int oa = __shfl_xor(am, msk, 64);
        float mm = fmaxf(m, om);
        ss = ss * __expf(m - mm) + os * __expf(om - mm);
        if (om > m || (om == m && oa < am)) am = oa;
        m = mm;
      }
      if (l31 == 0 && jok && npok) {
        size_t pb = (size_t)(t0 + j) * NP + np;
        __hip_atomic_store(&pmax[pb], m, __ATOMIC_RELAXED, __HIP_MEMORY_SCOPE_AGENT);
        __hip_atomic_store(&psum[pb], ss, __ATOMIC_RELAXED, __HIP_MEMORY_SCOPE_AGENT);
        __hip_atomic_store(&parg[pb], am, __ATOMIC_RELAXED, __HIP_MEMORY_SCOPE_AGENT);
      }
    }
  }
}

__device__ __forceinline__ void merge_row129(const float* pmax, const float* psum,
                                             const int* parg, int row, int lane,
                                             float& m, float& s, int& am) {
  size_t b = (size_t)row * NP;
  m = ld_coh(pmax + b + lane);
  s = ld_coh(psum + b + lane);
  am = __hip_atomic_load(&parg[b + lane], __ATOMIC_RELAXED, __HIP_MEMORY_SCOPE_AGENT);
  {
    int i2 = lane + 64;
    float om = ld_coh(pmax + b + i2);
    float os = ld_coh(psum + b + i2);
    int oa = __hip_atomic_load(&parg[b + i2], __ATOMIC_RELAXED, __HIP_MEMORY_SCOPE_AGENT);
    combine3(m, s, am, om, os, oa);
  }
  if (lane == 0) {
    float om = ld_coh(pmax + b + 128);
    float os = ld_coh(psum + b + 128);
    int oa = __hip_atomic_load(&parg[b + 128], __ATOMIC_RELAXED, __HIP_MEMORY_SCOPE_AGENT);
    combine3(m, s, am, om, os, oa);
  }
  #pragma unroll
  for (int msk = 32; msk; msk >>= 1) {
    float om = __shfl_xor(m, msk, 64);
    float os = __shfl_xor(s, msk, 64);
    int oa = __shfl_xor(am, msk, 64);
    combine3(m, s, am, om, os, oa);
  }
}

// ======================= K1: fused prep (gx GEMM + W_join->bf16) ===========
// blocks [0,416): gx tiles; blocks [416,1440): wconv stripes
__global__ __launch_bounds__(512) void prep_kernel(
    const float* __restrict__ Wih, const float* __restrict__ emb,
    const float* __restrict__ bl, const int* __restrict__ phon,
    const float* __restrict__ Wjoin, float* wsf) {
  extern __shared__ float sm[];
  const int tid = threadIdx.x;
  if (blockIdx.x >= 416) {
    // ---- wconv role ----
    __bf16* w16 = (__bf16*)(wsf + WSF_W16);
    int g0 = (blockIdx.x - 416) * 512 + tid;
    int gs = 1024 * 512;
    for (int q = g0; q < VD * 256; q += gs) {
      int v = q >> 8, seg = q & 255;
      float4 w4 = ((const float4*)(Wjoin + (size_t)v * 1024))[seg];
      bf16x4 r;
      r[0] = (__bf16)w4.x; r[1] = (__bf16)w4.y; r[2] = (__bf16)w4.z; r[3] = (__bf16)w4.w;
      *(bf16x4*)(w16 + (size_t)v * 1024 + (seg << 2)) = r;
    }
    return;
  }
  // ---- gx role ----
  float* Wt = sm;          // [16][132]
  float* Xt = sm + 2112;   // [16][68]
  float* gxT = wsf + WSF_GXT;
  const int tx = tid & 31, ty = tid >> 5;
  int ntiles = 32 * 13;    // 416
  for (int tile = blockIdx.x; tile < ntiles; tile += 416) {
    int vt = tile & 31, jt = tile >> 5;
    int v0 = vt * 128, j0 = jt * 64;
    float acc[4][4];
    #pragma unroll
    for (int a = 0; a < 4; ++a)
      #pragma unroll
      for (int q = 0; q < 4; ++q) acc[a][q] = 0.f;
    for (int kk = 0; kk < DEMB; kk += 16) {
      {
        int r = tid >> 2, seg = tid & 3;
        float4 wv = ((const float4*)(Wih + (size_t)(v0 + r) * DEMB + kk))[seg];
        Wt[(seg * 4 + 0) * 132 + r] = wv.x;
        Wt[(seg * 4 + 1) * 132 + r] = wv.y;
        Wt[(seg * 4 + 2) * 132 + r] = wv.z;
        Wt[(seg * 4 + 3) * 132 + r] = wv.w;
      }
      if (tid < 256) {
        int r = tid >> 2, seg = tid & 3;
        int j = j0 + r;
        float4 xv = make_float4(0.f, 0.f, 0.f, 0.f);
        if (j < NSTEP) {
          int tok = (j < 2) ? BLANK : phon[j - 2];
          xv = ((const float4*)(emb + (size_t)tok * DEMB + kk))[seg];
        }
        Xt[(seg * 4 + 0) * 68 + r] = xv.x;
        Xt[(seg * 4 + 1) * 68 + r] = xv.y;
        Xt[(seg * 4 + 2) * 68 + r] = xv.z;
        Xt[(seg * 4 + 3) * 68 + r] = xv.w;
      }
      __syncthreads();
      #pragma unroll
      for (int k = 0; k < 16; ++k) {
        float4 a = *(const float4*)(Wt + k * 132 + (tx << 2));
        float4 bq = *(const float4*)(Xt + k * 68 + (ty << 2));
        acc[0][0] = fmaf(a.x, bq.x, acc[0][0]); acc[1][0] = fmaf(a.y, bq.x, acc[1][0]);
        acc[2][0] = fmaf(a.z, bq.x, acc[2][0]); acc[3][0] = fmaf(a.w, bq.x, acc[3][0]);
        acc[0][1] = fmaf(a.x, bq.y, acc[0][1]); acc[1][1] = fmaf(a.y, bq.y, acc[1][1]);
        acc[2][1] = fmaf(a.z, bq.y, acc[2][1]); acc[3][1] = fmaf(a.w, bq.y, acc[3][1]);
        acc[0][2] = fmaf(a.x, bq.z, acc[0][2]); acc[1][2] = fmaf(a.y, bq.z, acc[1][2]);
        acc[2][2] = fmaf(a.z, bq.z, acc[2][2]); acc[3][2] = fmaf(a.w, bq.z, acc[3][2]);
        acc[0][3] = fmaf(a.x, bq.w, acc[0][3]); acc[1][3] = fmaf(a.y, bq.w, acc[1][3]);
        acc[2][3] = fmaf(a.z, bq.w, acc[2][3]); acc[3][3] = fmaf(a.w, bq.w, acc[3][3]);
      }
      __syncthreads();
    }
    int vb = v0 + (tx << 2), jb0 = j0 + (ty << 2);
    #pragma unroll
    for (int jj = 0; jj < 4; ++jj) {
      int j = jb0 + jj;
      if (j >= NSTEP) continue;
      #pragma unroll
      for (int q = 0; q < 4; ++q)
        gxT[(size_t)(vb + q) * NSTEPP + j] = acc[q][jj] + bl[vb + q];
    }
  }
}

// ======================= K2: sequential LSTM chain (coop, 256 WGs) ==========
// R8 protocol shape, but exchange packed 2x narrower: one u64 per 2 cells,
// payload {tag16|bf16h} per cell. Producer: 2 stores (was 4); consumer: one
// u64 atomic load per thread per retry (was two).
__global__ __launch_bounds__(NTHR) void chain_kernel(const float* __restrict__ Whh,
                                                     float* wsf) {
  extern __shared__ float sm[];
  float* gxl = sm;                  // [16][802] f32
  float* hb  = sm + 16 * NSTEPP;    // [2][1024]
  float* GS  = hb + 2048;           // [16]
  const int tid = threadIdx.x;
  const int w = tid >> 6, l = tid & 63;
  const int b = blockIdx.x;
  const float* gxT = wsf + WSF_GXT;
  float* hhist = wsf + WSF_HHIST;
  u64t* hx = (u64t*)(wsf + WSF_HX);   // [2][512] packed slots

  // register-resident Whh slices: wave w rows rr0=2w, rr1=2w+1 (rr = q*4+j)
  float4 W0[4], W1[4];
  {
    int rr0 = 2 * w, rr1 = 2 * w + 1;
    int gr0 = ((rr0 >> 2) << 10) + 4 * b + (rr0 & 3);
    int gr1 = ((rr1 >> 2) << 10) + 4 * b + (rr1 & 3);
    const float4* h0 = (const float4*)(Whh + (size_t)gr0 * HD);
    const float4* h1 = (const float4*)(Whh + (size_t)gr1 * HD);
    #pragma unroll
    for (int i = 0; i < 4; ++i) { W0[i] = h0[l + 64 * i]; W1[i] = h1[l + 64 * i]; }
  }
  for (int rr = 0; rr < 16; ++rr) {
    int gr = ((rr >> 2) << 10) + 4 * b + (rr & 3);
    for (int s = tid; s < NSTEP; s += NTHR)
      gxl[rr * NSTEPP + s] = gxT[(size_t)gr * NSTEPP + s];
  }
  for (int i = tid; i < 1024; i += NTHR) hb[i] = 0.f;   // h(0) = 0 in buffer 0
  __syncthreads();

  float c_reg = 0.f;
  for (int s = 0; s < NSTEP; ++s) {
    int p = s & 1;
    const float4* h4 = (const float4*)(hb + p * 1024);
    float a0 = 0.f, a1 = 0.f;
    #pragma unroll
    for (int i = 0; i < 4; ++i) {
      float4 hv = h4[l + 64 * i];
      a0 = dot4(W0[i], hv, a0);
      a1 = dot4(W1[i], hv, a1);
    }
    #pragma unroll
    for (int m = 32; m; m >>= 1) {
      a0 += __shfl_xor(a0, m, 64);
      a1 += __shfl_xor(a1, m, 64);
    }
    if (l == 0) { GS[2 * w] = a0; GS[2 * w + 1] = a1; }
    __syncthreads();
    if (tid < 4) {
      int j = tid;
      float gi = GS[j]      + gxl[j * NSTEPP + s];
      float gf = GS[4 + j]  + gxl[(4 + j) * NSTEPP + s];
      float gg = GS[8 + j]  + gxl[(8 + j) * NSTEPP + s];
      float go = GS[12 + j] + gxl[(12 + j) * NSTEPP + s];
      float c2 = sigm_fast(gf) * c_reg + sigm_fast(gi) * tanh_fast(gg);
      float h2 = sigm_fast(go) * tanh_fast(c2);
      c_reg = c2;
      int cell = 4 * b + j;
      // pack {tag16|bf16} per cell, pair cells via shfl, lanes {0,2} store u64
      unsigned hb16 = (unsigned)__builtin_bit_cast(unsigned short, (__bf16)h2);
      unsigned pk = (((unsigned)(s + 1)) << 16) | hb16;
      unsigned other = __shfl_xor(pk, 1, 64);   // lanes 0<->1, 2<->3 (all active)
      if ((tid & 1) == 0) {
        u64t pk2 = (u64t)pk | ((u64t)other << 32);
        __hip_atomic_store(&hx[((p ^ 1) << 9) + (cell >> 1)], pk2,
                           __ATOMIC_RELAXED, __HIP_MEMORY_SCOPE_AGENT);
      }
      hhist[(size_t)s * HD + cell] = h2;   // non-critical f32 history
    }
    if (s + 1 < NSTEP) {
      unsigned tg = (unsigned)(s + 1);
      const u64t* src = hx + ((p ^ 1) << 9);
      u64t v;
      do {  // ONE u64 load in flight per retry, no sleep
        v = __hip_atomic_load(&src[tid], __ATOMIC_RELAXED, __HIP_MEMORY_SCOPE_AGENT);
      } while (((unsigned)(v >> 16) & 0xFFFFu) != tg || (unsigned)(v >> 48) != tg);
      float* dst = hb + (p ^ 1) * 1024 + 2 * tid;
      dst[0] = bfbits_to_f32((unsigned)v);
      dst[1] = bfbits_to_f32((unsigned)(v >> 32));
    }
    __syncthreads();
  }
}

// ======================= K2b: preds = W_pred @ hhist + bp ===================
__global__ __launch_bounds__(512) void preds_kernel(
    const float* __restrict__ Wpred, const float* __restrict__ bp, float* wsf) {
  extern __shared__ float sm[];
  float* Wt = sm;
  float* Xt = sm + 2112;
  const float* hhist = wsf + WSF_HHIST;
  float* preds = wsf + WSF_PREDS;
  const int tid = threadIdx.x;
  const int tx = tid & 31, ty = tid >> 5;
  int ntiles = 8 * 13;
  for (int tile = blockIdx.x; tile < ntiles; tile += gridDim.x) {
    int vt = tile & 7, jt = tile >> 3;
    int v0 = vt * 128, j0 = jt * 64;
    float acc[4][4];
    #pragma unroll
    for (int a = 0; a < 4; ++a)
      #pragma unroll
      for (int q = 0; q < 4; ++q) acc[a][q] = 0.f;
    for (int kk = 0; kk < 1024; kk += 16) {
      {
        int r = tid >> 2, seg = tid & 3;
        float4 wv = ((const float4*)(Wpred + (size_t)(v0 + r) * HD + kk))[seg];
        Wt[(seg * 4 + 0) * 132 + r] = wv.x;
        Wt[(seg * 4 + 1) * 132 + r] = wv.y;
        Wt[(seg * 4 + 2) * 132 + r] = wv.z;
        Wt[(seg * 4 + 3) * 132 + r] = wv.w;
      }
      if (tid < 256) {
        int r = tid >> 2, seg = tid & 3;
        int j = j0 + r;
        float4 xv = make_float4(0.f, 0.f, 0.f, 0.f);
        if (j <= NPH) xv = ((const float4*)(hhist + (size_t)(j + 1) * HD + kk))[seg];
        Xt[(seg * 4 + 0) * 68 + r] = xv.x;
        Xt[(seg * 4 + 1) * 68 + r] = xv.y;
        Xt[(seg * 4 + 2) * 68 + r] = xv.z;
        Xt[(seg * 4 + 3) * 68 + r] = xv.w;
      }
      __syncthreads();
      #pragma unroll
      for (int k = 0; k < 16; ++k) {
        float4 a = *(const float4*)(Wt + k * 132 + (tx << 2));
        float4 bq = *(const float4*)(Xt + k * 68 + (ty << 2));
        acc[0][0] = fmaf(a.x, bq.x, acc[0][0]); acc[1][0] = fmaf(a.y, bq.x, acc[1][0]);
        acc[2][0] = fmaf(a.z, bq.x, acc[2][0]); acc[3][0] = fmaf(a.w, bq.x, acc[3][0]);
        acc[0][1] = fmaf(a.x, bq.y, acc[0][1]); acc[1][1] = fmaf(a.y, bq.y, acc[1][1]);
        acc[2][1] = fmaf(a.z, bq.y, acc[2][1]); acc[3][1] = fmaf(a.w, bq.y, acc[3][1]);
        acc[0][2] = fmaf(a.x, bq.z, acc[0][2]); acc[1][2] = fmaf(a.y, bq.z, acc[1][2]);
        acc[2][2] = fmaf(a.z, bq.z, acc[2][2]); acc[3][2] = fmaf(a.w, bq.z, acc[3][2]);
        acc[0][3] = fmaf(a.x, bq.w, acc[0][3]); acc[1][3] = fmaf(a.y, bq.w, acc[1][3]);
        acc[2][3] = fmaf(a.z, bq.w, acc[2][3]); acc[3][3] = fmaf(a.w, bq.w, acc[3][3]);
      }
      __syncthreads();
    }
    int vb = v0 + (tx << 2), jb0 = j0 + (ty << 2);
    #pragma unroll
    for (int jj = 0; jj < 4; ++jj) {
      int j = jb0 + jj;
      if (j > NPH) continue;
      #pragma unroll
      for (int q = 0; q < 4; ++q)
        preds[(size_t)j * 1024 + vb + q] = acc[q][jj] + bp[vb + q];
    }
  }
}

// ======================= K2c: speculative-chunk xbf =========================
__global__ void xspec_kernel(const float* __restrict__ enc, float* wsf) {
  xbf_fill(enc, wsf + WSF_PREDS, (__bf16*)(wsf + WSF_XBF), 0, CHUNK_M, 0,
           blockIdx.x * blockDim.x + threadIdx.x, gridDim.x * blockDim.x);
}

// ======================= K3a: speculative joiner (plain) ====================
__global__ __launch_bounds__(NTHR) void joinspec_kernel(const float* __restrict__ bj,
                                                        float* out, float* wsf) {
  extern __shared__ float sm[];
  joiner_tiles((__bf16*)(wsf + WSF_W16), (__bf16*)(wsf + WSF_XBF), bj, out,
               wsf + WSF_PMAX, wsf + WSF_PSUM, (int*)(wsf + WSF_PARG),
               (char*)sm, 0, CHUNK_M, blockIdx.x, gridDim.x);
}

// ======================= K3b: decode loop (coop) ============================
__global__ __launch_bounds__(NTHR) void decode_coop(
    const float* enc, const float* bj, const int* phon, float* out, float* wsf) {
  extern __shared__ float sm[];
  char* smc = (char*)sm;
  unsigned* flags = (unsigned*)wsf;
  float* preds = wsf + WSF_PREDS;
  float* pmax = wsf + WSF_PMAX;
  float* psum = wsf + WSF_PSUM;
  int* parg = (int*)(wsf + WSF_PARG);
  float* lse = wsf + WSF_LSE;
  int* amaxws = (int*)(wsf + WSF_AMAX);
  __bf16* xbf = (__bf16*)(wsf + WSF_XBF);
  __bf16* w16 = (__bf16*)(wsf + WSF_W16);
  float* out_pred  = out + (size_t)TT * VD;
  float* out_valid = out + (size_t)TT * VD + TT;

  const int tid = threadIdx.x;
  const int wid = tid >> 6, lane = tid & 63;
  unsigned ep = 1;
  int t = 0, tp = 0, iter = 0;

  while (t < TT && tp < NPH) {
    int K = CHUNK_M;
    if (TT - t < K) K = TT - t;
    if (NPH - tp < K) K = NPH - tp;
    if (iter > 0) {   // rare rollback: recompute chunk with corrected preds
      heavy_barrier(flags);
      xbf_fill(enc, preds, xbf, t, K, tp, blockIdx.x * NTHR + tid, gridDim.x * NTHR);
      heavy_barrier(flags);
      joiner_tiles(w16, xbf, bj, out, pmax, psum, parg, smc, t, K,
                   blockIdx.x, gridDim.x);
    }
    light_barrier(flags, ep);
    for (int j = blockIdx.x * 8 + wid; j < K; j += gridDim.x * 8) {
      float m, s; int am;
      merge_row129(pmax, psum, parg, t + j, lane, m, s, am);
      if (lane == 0) {
        __hip_atomic_store(&amaxws[j], am, __ATOMIC_RELAXED, __HIP_MEMORY_SCOPE_AGENT);
        lse[t + j] = m + logf(s);
      }
    }
    light_barrier(flags, ep);
    int cand = K;
    for (int idx = tid; idx < K; idx += NTHR) {
      int a = __hip_atomic_load(&amaxws[idx], __ATOMIC_RELAXED, __HIP_MEMORY_SCOPE_AGENT);
      if (a == BLANK && idx < cand) cand = idx;
    }
    #pragma unroll
    for (int msk = 32; msk; msk >>= 1) cand = min(cand, __shfl_xor(cand, msk, 64));
    int* red = (int*)(smc + 65536);
    if (lane == 0) red[wid] = cand;
    __syncthreads();
    if (tid == 0) {
      int mn = red[0];
      for (int w2 = 1; w2 < 8; ++w2) mn = min(mn, red[w2]);
      red[8] = mn;
    }
    __syncthreads();
    int jb = red[8];
    __syncthreads();
    int nacc = (jb < K) ? jb + 1 : K;
    int nadv = (jb < K) ? jb : K;
    if (blockIdx.x == 0) {
      for (int j = tid; j < nacc; j += NTHR) {
        out_pred[t + j] = (j == jb) ? (float)BLANK : (float)phon[tp + j];
        out_valid[t + j] = 1.f;
      }
    }
    t += nacc; tp += nadv; ++iter;
  }

  if (t < TT) {
    xbf_fill(enc, preds, xbf + (size_t)(t - 800) * 1024, t, TT - t, -1,
             blockIdx.x * NTHR + tid, gridDim.x * NTHR);
  }
  if (blockIdx.x == 0 && tid == 0) ((int*)wsf)[TST_IDX] = t;
}

// ======================= K4: tail joiner (plain) ============================
__global__ __launch_bounds__(NTHR) void jointail_kernel(const float* __restrict__ bj,
                                                        float* out, float* wsf) {
  extern __shared__ float sm[];
  int t = ((const int*)wsf)[TST_IDX];
  if (t >= TT) return;
  joiner_tiles((__bf16*)(wsf + WSF_W16),
               (__bf16*)(wsf + WSF_XBF) + (size_t)(t - 800) * 1024, bj, out,
               wsf + WSF_PMAX, wsf + WSF_PSUM, (int*)(wsf + WSF_PARG),
               (char*)sm, t, TT - t, blockIdx.x, gridDim.x);
}

// ======================= K5: tail merge -> lse, pred/valid ==================
__global__ __launch_bounds__(NTHR) void mergetail_kernel(float* out, float* wsf) {
  int t = ((const int*)wsf)[TST_IDX];
  float* lse = wsf + WSF_LSE;
  float* out_pred  = out + (size_t)TT * VD;
  float* out_valid = out + (size_t)TT * VD + TT;
  const int wid = threadIdx.x >> 6, lane = threadIdx.x & 63;
  for (int row = t + blockIdx.x * 8 + wid; row < TT; row += gridDim.x * 8) {
    float m, s; int am;
    merge_row129(wsf + WSF_PMAX, wsf + WSF_PSUM, (const int*)(wsf + WSF_PARG),
                 row, lane, m, s, am);
    if (lane == 0) {
      lse[row] = m + logf(s);
      out_pred[row] = (float)BLANK;
      out_valid[row] = 0.f;
    }
  }
}

// ======================= K6: logp = logits - lse (float4) ===================
__global__ __launch_bounds__(256) void sub_kernel(float* out, const float* wsf) {
  const float* lse = wsf + WSF_LSE;
  for (int row = blockIdx.x; row < TT; row += gridDim.x) {
    float l = lse[row];
    float4* p4 = (float4*)(out + (size_t)row * VD);
    #pragma unroll
    for (int k = 0; k < 8; ++k) {
      int i = threadIdx.x + k * 256;   // 2048 float4 cover 8192 floats
      float4 v = p4[i];
      v.x -= l; v.y -= l; v.z -= l; v.w -= l;
      p4[i] = v;
    }
    if (threadIdx.x == 0) out[(size_t)row * VD + 8192] -= l;
  }
}

// ======================= f32 fallback (round-3/4, proven) ===================
struct Ctx {
  const float *enc, *emb, *Wih, *Whh, *bl, *Wpred, *bp, *Wjoin, *bj;
  const int* phon;
  unsigned long long* hx;
  float *hhist, *preds, *pmax, *psum, *lse;
  int* parg;
  unsigned* flags;
  float *out_align, *out_pred, *out_valid;
};

__device__ void chain_all_legacy(const Ctx& C, float* sm) {
  const int tid = threadIdx.x;
  const int w = tid >> 6, l = tid & 63;
  const int b = blockIdx.x;
  int* tok_sm = (int*)(sm + S_TOK);
  for (int s = tid; s < NSTEP; s += NTHR)
    tok_sm[s] = (s < 2) ? BLANK : C.phon[s - 2];
  float4 W0[6], W1[6];
  {
    int rr0 = 2 * w, rr1 = 2 * w + 1;
    int gr0 = ((rr0 >> 2) << 10) + 4 * b + (rr0 & 3);
    int gr1 = ((rr1 >> 2) << 10) + 4 * b + (rr1 & 3);
    const float4* ih0 = (const float4*)(C.Wih + (size_t)gr0 * DEMB);
    const float4* hh0 = (const float4*)(C.Whh + (size_t)gr0 * HD);
    const float4* ih1 = (const float4*)(C.Wih + (size_t)gr1 * DEMB);
    const float4* hh1 = (const float4*)(C.Whh + (size_t)gr1 * HD);
    W0[0] = ih0[l];       W0[1] = ih0[64 + l];
    W0[2] = hh0[l];       W0[3] = hh0[64 + l];
    W0[4] = hh0[128 + l]; W0[5] = hh0[192 + l];
    W1[0] = ih1[l];       W1[1] = ih1[64 + l];
    W1[2] = hh1[l];       W1[3] = hh1[64 + l];
    W1[4] = hh1[128 + l]; W1[5] = hh1[192 + l];
  }
  float bi = 0.f, bf = 0.f, bg = 0.f, bo = 0.f;
  if (tid < 4) {
    bi = C.bl[4 * b + tid];
    bf = C.bl[1024 + 4 * b + tid];
    bg = C.bl[2048 + 4 * b + tid];
    bo = C.bl[3072 + 4 * b + tid];
    sm[S_C4 + tid] = 0.f;
  }
  for (int i = tid; i < 1536; i += NTHR) sm[S_XH + i] = 0.f;
  if (tid < 512) sm[S_XH + tid] = C.emb[(size_t)BLANK * DEMB + tid];
  __syncthreads();
  unsigned long long* hx = C.hx;
  for (int s = 0; s < NSTEP; ++s) {
    int p = s & 1;
    const float4* xh4 = (const float4*)(sm + S_XH + p * 1536);
    float a0 = 0.f, a1 = 0.f;
    #pragma unroll
    for (int i = 0; i < 6; ++i) {
      float4 v = xh4[i * 64 + l];
      a0 = dot4(W0[i], v, a0);
      a1 = dot4(W1[i], v, a1);
    }
    #pragma unroll
    for (int m = 32; m; m >>= 1) {
      a0 += __shfl_xor(a0, m, 64);
      a1 += __shfl_xor(a1, m, 64);
    }
    if (l == 0) { sm[S_GS + 2 * w] = a0; sm[S_GS + 2 * w + 1] = a1; }
    if (s + 1 < NSTEP && tid < 512)
      sm[S_XH + (1 - p) * 1536 + tid] = C.emb[(size_t)tok_sm[s + 1] * DEMB + tid];
    __syncthreads();
    if (tid < 4) {
      int j = tid;
      float gi = sm[S_GS + j]      + bi;
      float gf = sm[S_GS + 4 + j]  + bf;
      float gg = sm[S_GS + 8 + j]  + bg;
      float go = sm[S_GS + 12 + j] + bo;
      float cc = sm[S_C4 + j];
      float c2 = sigmf(gf) * cc + sigmf(gi) * tanhf(gg);
      float h2 = sigmf(go) * tanhf(c2);
      sm[S_C4 + j] = c2;
      int cell = 4 * b + j;
      C.hhist[(size_t)s * HD + cell] = h2;
      unsigned long long pk = ((unsigned long long)(unsigned)(s + 1) << 32)
                            | (unsigned long long)__float_as_uint(h2);
      __hip_atomic_store(&hx[(1 - p) * 1024 + cell], pk,
                         __ATOMIC_RELAXED, __HIP_MEMORY_SCOPE_AGENT);
    }
    if (s + 1 < NSTEP) {
      unsigned tg = (unsigned)(s + 1);
      #pragma unroll
      for (int kq = 0; kq < 2; ++kq) {
        int k = tid + kq * 512;
        unsigned long long v;
        do {
          v = __hip_atomic_load(&hx[(1 - p) * 1024 + k],
                                __ATOMIC_RELAXED, __HIP_MEMORY_SCOPE_AGENT);
        } while ((unsigned)(v >> 32) != tg);
        sm[S_XH + (1 - p) * 1536 + 512 + k] = __uint_as_float((unsigned)v);
      }
    }
    __syncthreads();
  }
}

__device__ void preds_gemm_legacy(const Ctx& C, float* sm) {
  float* Wt = sm;
  float* Xt = sm + 2112;
  const int tid = threadIdx.x;
  const int tx = tid & 31, ty = tid >> 5;
  int ntiles = 8 * 13;
  for (int tile = blockIdx.x; tile < ntiles; tile += NWG) {
    int vt = tile & 7, jt = tile >> 3;
    int v0 = vt * 128, j0 = jt * 64;
    float acc[4][4];
    #pragma unroll
    for (int a = 0; a < 4; ++a)
      #pragma unroll
      for (int q = 0; q < 4; ++q) acc[a][q] = 0.f;
    for (int kk = 0; kk < 1024; kk += 16) {
      {
        int r = tid >> 2, seg = tid & 3;
        float4 wv = ((const float4*)(C.Wpred + (size_t)(v0 + r) * HD + kk))[seg];
        Wt[(seg * 4 + 0) * 132 + r] = wv.x;
        Wt[(seg * 4 + 1) * 132 + r] = wv.y;
        Wt[(seg * 4 + 2) * 132 + r] = wv.z;
        Wt[(seg * 4 + 3) * 132 + r] = wv.w;
      }
      if (tid < 256) {
        int r = tid >> 2, seg = tid & 3;
        int j = j0 + r;
        float4 xv = make_float4(0.f, 0.f, 0.f, 0.f);
        if (j <= NPH) xv = ((const float4*)(C.hhist + (size_t)(j + 1) * HD + kk))[seg];
        Xt[(seg * 4 + 0) * 68 + r] = xv.x;
        Xt[(seg * 4 + 1) * 68 + r] = xv.y;
        Xt[(seg * 4 + 2) * 68 + r] = xv.z;
        Xt[(seg * 4 + 3) * 68 + r] = xv.w;
      }
      __syncthreads();
      #pragma unroll
      for (int k = 0; k < 16; ++k) {
        float4 a = *(const float4*)(Wt + k * 132 + (tx << 2));
        float4 bq = *(const float4*)(Xt + k * 68 + (ty << 2));
        acc[0][0] = fmaf(a.x, bq.x, acc[0][0]); acc[1][0] = fmaf(a.y, bq.x, acc[1][0]);
        acc[2][0] = fmaf(a.z, bq.x, acc[2][0]); acc[3][0] = fmaf(a.w, bq.x, acc[3][0]);
        acc[0][1] = fmaf(a.x, bq.y, acc[0][1]); acc[1][1] = fmaf(a.y, bq.y, acc[1][1]);
        acc[2][1] = fmaf(a.z, bq.y, acc[2][1]); acc[3][1] = fmaf(a.w, bq.y, acc[3][1]);
        acc[0][2] = fmaf(a.x, bq.z, acc[0][2]); acc[1][2] = fmaf(a.y, bq.z, acc[1][2]);
        acc[2][2] = fmaf(a.z, bq.z, acc[2][2]); acc[3][2] = fmaf(a.w, bq.z, acc[3][2]);
        acc[0][3] = fmaf(a.x, bq.w, acc[0][3]); acc[1][3] = fmaf(a.y, bq.w, acc[1][3]);
        acc[2][3] = fmaf(a.z, bq.w, acc[2][3]); acc[3][3] = fmaf(a.w, bq.w, acc[3][3]);
      }
      __syncthreads();
    }
    int vb = v0 + (tx << 2), jb0 = j0 + (ty << 2);
    #pragma unroll
    for (int jj = 0; jj < 4; ++jj) {
      int j = jb0 + jj;
      if (j > NPH) continue;
      #pragma unroll
      for (int q = 0; q < 4; ++q)
        C.preds[(size_t)j * 1024 + vb + q] = acc[q][jj] + C.bp[vb + q];
    }
  }
}

__device__ void joiner_gemm_f32(const Ctx& C, float* sm, int t0, int K, int pi0) {
  float* Wt = sm;
  float* Xt = sm + 2112;
  const int tid = threadIdx.x;
  const int tx = tid & 31, ty = tid >> 5;
  int jt_n = (K + 63) >> 6;
  int ntiles = jt_n * NVT;
  for (int tile = blockIdx.x; tile < ntiles; tile += NWG) {
    int vt = tile % NVT, jt = tile / NVT;
    int v0 = vt * 128, j0 = jt * 64;
    float acc[4][4];
    #pragma unroll
    for (int a = 0; a < 4; ++a)
      #pragma unroll
      for (int q = 0; q < 4; ++q) acc[a][q] = 0.f;
    for (int kk = 0; kk < 1024; kk += 16) {
      {
        int r = tid >> 2, seg = tid & 3;
        int v = v0 + r;
        float4 wv = make_float4(0.f, 0.f, 0.f, 0.f);
        if (v < VD) wv = ((const float4*)(C.Wjoin + (size_t)v * 1024 + kk))[seg];
        Wt[(seg * 4 + 0) * 132 + r] = wv.x;
        Wt[(seg * 4 + 1) * 132 + r] = wv.y;
        Wt[(seg * 4 + 2) * 132 + r] = wv.z;
        Wt[(seg * 4 + 3) * 132 + r] = wv.w;
      }
      if (tid < 256) {
        int r = tid >> 2, seg = tid & 3;
        int j = j0 + r;
        float4 xv = make_float4(0.f, 0.f, 0.f, 0.f);
        if (j < K) {
          int pi = (pi0 < 0) ? NPH : (pi0 + j);
          float4 e = ((const float4*)(C.enc + (size_t)(t0 + j) * DENC + kk))[seg];
          float4 pr = ((const float4*)(C.preds + (size_t)pi * 1024 + kk))[seg];
          xv.x = fmaxf(e.x + pr.x, 0.f);
          xv.y = fmaxf(e.y + pr.y, 0.f);
          xv.z = fmaxf(e.z + pr.z, 0.f);
          xv.w = fmaxf(e.w + pr.w, 0.f);
        }
        Xt[(seg * 4 + 0) * 68 + r] = xv.x;
        Xt[(seg * 4 + 1) * 68 + r] = xv.y;
        Xt[(seg * 4 + 2) * 68 + r] = xv.z;
        Xt[(seg * 4 + 3) * 68 + r] = xv.w;
      }
      __syncthreads();
      #pragma unroll
      for (int k = 0; k < 16; ++k) {
        float4 a = *(const float4*)(Wt + k * 132 + (tx << 2));
        float4 bq = *(const float4*)(Xt + k * 68 + (ty << 2));
        acc[0][0] = fmaf(a.x, bq.x, acc[0][0]); acc[1][0] = fmaf(a.y, bq.x, acc[1][0]);
        acc[2][0] = fmaf(a.z, bq.x, acc[2][0]); acc[3][0] = fmaf(a.w, bq.x, acc[3][0]);
        acc[0][1] = fmaf(a.x, bq.y, acc[0][1]); acc[1][1] = fmaf(a.y, bq.y, acc[1][1]);
        acc[2][1] = fmaf(a.z, bq.y, acc[2][1]); acc[3][1] = fmaf(a.w, bq.y, acc[3][1]);
        acc[0][2] = fmaf(a.x, bq.z, acc[0][2]); acc[1][2] = fmaf(a.y, bq.z, acc[1][2]);
        acc[2][2] = fmaf(a.z, bq.z, acc[2][2]); acc[3][2] = fmaf(a.w, bq.z, acc[3][2]);
        acc[0][3] = fmaf(a.x, bq.w, acc[0][3]); acc[1][3] = fmaf(a.y, bq.w, acc[1][3]);
        acc[2][3] = fmaf(a.z, bq.w, acc[2][3]); acc[3][3] = fmaf(a.w, bq.w, acc[3][3]);
      }
      __syncthreads();
    }
    int vb = v0 + (tx << 2);
    int jb0 = j0 + (ty << 2);
    float bjv[4];
    #pragma unroll
    for (int q = 0; q < 4; ++q) bjv[q] = (vb + q < VD) ? C.bj[vb + q] : 0.f;
    #pragma unroll
    for (int jj = 0; jj < 4; ++jj) {
      int j = jb0 + jj;
      if (j >= K) continue;
      size_t ro = (size_t)(t0 + j) * VD;
      float lg[4];
      float m = -1e30f; int am = vb;
      #pragma unroll
      for (int q = 0; q < 4; ++q) {
        int v = vb + q;
        if (v < VD) {
          lg[q] = acc[q][jj] + bjv[q];
          C.out_align[ro + v] = lg[q];
          if (lg[q] > m) { m = lg[q]; am = v; }
        } else lg[q] = -1e30f;
      }
      float ss = 0.f;
      #pragma unroll
      for (int q = 0; q < 4; ++q)
        if (vb + q < VD) ss += __expf(lg[q] - m);
      #pragma unroll
      for (int msk = 16; msk; msk >>= 1) {
        float om = __shfl_xor(m, msk, 64);
        float os = __shfl_xor(ss, msk, 64);
        int oa = __shfl_xor(am, msk, 64);
        combine3(m, ss, am, om, os, oa);
      }
      if (tx == 0) {
        size_t pb = (size_t)(t0 + j) * NVT + vt;
        __hip_atomic_store(&C.pmax[pb], m, __ATOMIC_RELAXED, __HIP_MEMORY_SCOPE_AGENT);
        __hip_atomic_store(&C.psum[pb], ss, __ATOMIC_RELAXED, __HIP_MEMORY_SCOPE_AGENT);
        __hip_atomic_store(&C.parg[pb], am, __ATOMIC_RELAXED, __HIP_MEMORY_SCOPE_AGENT);
      }
    }
  }
}

__device__ __forceinline__ void merge_row65(const Ctx& C, int row, int lane,
                                            float& m, float& s, int& am) {
  size_t b = (size_t)row * NVT;
  m = ld_coh(C.pmax + b + lane);
  s = ld_coh(C.psum + b + lane);
  am = __hip_atomic_load(&C.parg[b + lane], __ATOMIC_RELAXED, __HIP_MEMORY_SCOPE_AGENT);
  if (lane == 0) {
    float om = ld_coh(C.pmax + b + 64);
    float os = ld_coh(C.psum + b + 64);
    int oa = __hip_atomic_load(&C.parg[b + 64], __ATOMIC_RELAXED, __HIP_MEMORY_SCOPE_AGENT);
    combine3(m, s, am, om, os, oa);
  }
  #pragma unroll
  for (int msk = 32; msk; msk >>= 1) {
    float om = __shfl_xor(m, msk, 64);
    float os = __shfl_xor(s, msk, 64);
    int oa = __shfl_xor(am, msk, 64);
    combine3(m, s, am, om, os, oa);
  }
}

__global__ __launch_bounds__(NTHR) void decode_kernel_f32(
    const float* enc, const float* emb, const float* Wih, const float* Whh,
    const float* bl, const float* Wpred, const float* bp, const float* Wjoin,
    const float* bj, const int* phon, float* out, float* wsf) {
  extern __shared__ float sm[];
  Ctx C;
  C.enc = enc; C.emb = emb; C.Wih = Wih; C.Whh = Whh; C.bl = bl;
  C.Wpred = Wpred; C.bp = bp; C.Wjoin = Wjoin; C.bj = bj; C.phon = phon;
  C.flags = (unsigned*)wsf;
  C.hx = (unsigned long long*)(wsf + L_HX);
  C.hhist = wsf + L_HHIST;
  C.preds = wsf + L_PREDS;
  C.pmax = wsf + F_PMAX;
  C.psum = wsf + F_PSUM;
  C.parg = (int*)(wsf + F_PARG);
  C.lse = wsf + F_LSE;
  C.out_align = out;
  C.out_pred  = out + (size_t)TT * VD;
  C.out_valid = out + (size_t)TT * VD + TT;

  const int tid = threadIdx.x;
  const int wid = tid >> 6, lane = tid & 63;
  unsigned ep = 1;

  chain_all_legacy(C, sm);
  heavy_barrier(C.flags);
  preds_gemm_legacy(C, sm);
  heavy_barrier(C.flags);

  int t = 0, tp = 0;
  while (t < TT && tp < NPH) {
    int K = CHUNK;
    if (TT - t < K) K = TT - t;
    if (NPH - tp < K) K = NPH - tp;
    joiner_gemm_f32(C, sm, t, K, tp);
    light_barrier(C.flags, ep);
    int* amax_l = (int*)(sm + S_AMAX);
    for (int j = wid; j < K; j += 8) {
      float m, s; int am;
      merge_row65(C, t + j, lane, m, s, am);
      if (lane == 0) {
        amax_l[j] = am;
        C.lse[t + j] = m + logf(s);
      }
    }
    __syncthreads();
    int cand = K;
    if (tid < K && amax_l[tid] == BLANK) cand = tid;
    #pragma unroll
    for (int msk = 32; msk; msk >>= 1) cand = min(cand, __shfl_xor(cand, msk, 64));
    int* red = (int*)(sm + S_RED);
    if (lane == 0) red[wid] = cand;
    __syncthreads();
    if (tid == 0) {
      int mn = red[0];
      for (int w2 = 1; w2 < 8; ++w2) mn = min(mn, red[w2]);
      red[8] = mn;
    }
    __syncthreads();
    int jb = red[8];
    __syncthreads();
    int nacc = (jb < K) ? jb + 1 : K;
    int nadv = (jb < K) ? jb : K;
    if (blockIdx.x == 0) {
      int* tok_sm = (int*)(sm + S_TOK);
      for (int j = tid; j < nacc; j += NTHR) {
        C.out_pred[t + j] = (j == jb) ? (float)BLANK : (float)tok_sm[tp + j + 2];
        C.out_valid[t + j] = 1.f;
      }
    }
    t += nacc; tp += nadv;
    if (jb < K) heavy_barrier(C.flags);
  }
  if (t < TT) {
    int Kt = TT - t;
    joiner_gemm_f32(C, sm, t, Kt, -1);
    light_barrier(C.flags, ep);
    for (int i = blockIdx.x * 8 + wid; i < Kt; i += NWG * 8) {
      float m, s; int am;
      merge_row65(C, t + i, lane, m, s, am);
      if (lane == 0) C.lse[t + i] = m + logf(s);
    }
    const int gtid = blockIdx.x * NTHR + tid;
    for (int i = gtid; i < Kt; i += NWG * NTHR) {
      C.out_pred[t + i] = (float)BLANK;
      C.out_valid[t + i] = 0.f;
    }
  }
  heavy_barrier(C.flags);
  for (int row = blockIdx.x; row < TT; row += NWG) {
    float l = C.lse[row];
    float* p = C.out_align + (size_t)row * VD;
    for (int i = tid; i < VD; i += NTHR) p[i] -= l;
  }
}

// ======================= host =======================

extern "C" void kernel_launch(void* const* d_in, const int* in_sizes, int n_in,
                              void* d_out, int out_size, void* d_ws, size_t ws_size,
                              hipStream_t stream) {
  const float* enc   = (const float*)d_in[0];
  const float* emb   = (const float*)d_in[1];
  const float* Wih   = (const float*)d_in[2];
  const float* Whh   = (const float*)d_in[3];
  const float* bl    = (const float*)d_in[4];
  const float* Wpred = (const float*)d_in[5];
  const float* bp    = (const float*)d_in[6];
  const float* Wjoin = (const float*)d_in[7];
  const float* bj    = (const float*)d_in[8];
  const int*   phon  = (const int*)d_in[9];
  float* out = (float*)d_out;
  float* wsf = (float*)d_ws;

  // flags + packed h-exchange must start clean every call (tag 0 != any s+1)
  hipMemsetAsync(d_ws, 0, MEMSET_BYTES, stream);

  if (ws_size >= NEED_MFMA) {
    hipFuncSetAttribute((const void*)chain_kernel,
                        hipFuncAttributeMaxDynamicSharedMemorySize, CHAIN_SMEM);
    hipFuncSetAttribute((const void*)joinspec_kernel,
                        hipFuncAttributeMaxDynamicSharedMemorySize, JOIN_SMEM);
    hipFuncSetAttribute((const void*)decode_coop,
                        hipFuncAttributeMaxDynamicSharedMemorySize, JOIN_SMEM);
    hipFuncSetAttribute((const void*)jointail_kernel,
                        hipFuncAttributeMaxDynamicSharedMemorySize, JOIN_SMEM);

    prep_kernel<<<1440, 512, GEMM_SMEM, stream>>>(Wih, emb, bl, phon, Wjoin, wsf);
    {
      const float* WhhA = Whh; float* wsfA = wsf;
      void* a2[] = { &WhhA, &wsfA };
      hipError_t e = hipLaunchCooperativeKernel((void*)chain_kernel, dim3(256), dim3(NTHR),
                                                a2, CHAIN_SMEM, stream);
      if (e != hipSuccess)
        chain_kernel<<<dim3(256), dim3(NTHR), CHAIN_SMEM, stream>>>(Whh, wsf);
    }
    preds_kernel<<<104, 512, GEMM_SMEM, stream>>>(Wpred, bp, wsf);
    xspec_kernel<<<1024, 256, 0, stream>>>(enc, wsf);
    joinspec_kernel<<<455, NTHR, JOIN_SMEM, stream>>>(bj, out, wsf);
    {
      const float* encA = enc; const float* bjA = bj; const int* phonA = phon;
      float* outA = out; float* wsfA = wsf;
      void* a3[] = { &encA, &bjA, &phonA, &outA, &wsfA };
      hipError_t e = hipLaunchCooperativeKernel((void*)decode_coop, dim3(NWG), dim3(NTHR),
                                                a3, JOIN_SMEM, stream);
      if (e != hipSuccess)
        decode_coop<<<dim3(NWG), dim3(NTHR), JOIN_SMEM, stream>>>(enc, bj, phon, out, wsf);
    }
    jointail_kernel<<<1664, NTHR, JOIN_SMEM, stream>>>(bj, out, wsf);
    mergetail_kernel<<<256, NTHR, 0, stream>>>(out, wsf);
    sub_kernel<<<2048, 256, 0, stream>>>(out, wsf);
  } else {
    hipFuncSetAttribute((const void*)decode_kernel_f32,
                        hipFuncAttributeMaxDynamicSharedMemorySize, SMEM_BYTES_F32);
    void* args[] = { &enc, &emb, &Wih, &Whh, &bl, &Wpred, &bp, &Wjoin, &bj, &phon, &out, &wsf };
    hipError_t e = hipLaunchCooperativeKernel((void*)decode_kernel_f32, dim3(NWG), dim3(NTHR),
                                              args, SMEM_BYTES_F32, stream);
    if (e != hipSuccess) {
      decode_kernel_f32<<<dim3(NWG), dim3(NTHR), SMEM_BYTES_F32, stream>>>(
          enc, emb, Wih, Whh, bl, Wpred, bp, Wjoin, bj, phon, out, wsf);
    }
  }
}

// Round 10
// 2680.061 us; speedup vs baseline: 1.0782x; 1.0782x over previous
//
#include <hip/hip_runtime.h>
#include <math.h>

#define TT     4000
#define DENC   1024
#define HD     1024
#define DEMB   512
#define VD     8193
#define NPH    800
#define BLANK  8192
#define NWG    256
#define NTHR   512
#define CHUNK_M 800
#define NSTEP  (NPH + 2)   // 802 sequential LSTM steps
#define NSTEPP 802
#define NVT    65          // v-tiles of 128
#define NP     129         // v-blocks of 64 (mfma partials per row)
#define CHUNK  256         // f32 fallback chunk

typedef __bf16 bf16x4 __attribute__((ext_vector_type(4)));
typedef __bf16 bf16x8 __attribute__((ext_vector_type(8)));
typedef float  f32x16 __attribute__((ext_vector_type(16)));

// ---- workspace layout (float offsets), mfma path (R4/R8-proven) ----
#define MEMSET_BYTES 20480
#define WSF_HX     1024                          // u64[2][1024] tagged h exchange
#define WSF_HHIST  5120                          // NSTEP x 1024 f32
#define WSF_PREDS  826368                        // 801 x 1024 f32
#define WSF_GXT    826368                        // ALIAS: gxT[4096][802] f32 (dead after chain)
#define WSF_PMAX   1646592                       // TT*NP
#define WSF_PSUM   2162592
#define WSF_PARG   2678592
#define WSF_LSE    3194592
#define WSF_AMAX   3198592                       // 1024 ints
#define WSF_XBF    3199616                       // bf16 3328x1024
#define WSF_W16    4903552                       // bf16 8320x1024
#define WSF_END    9163392
#define NEED_MFMA  ((size_t)WSF_END * 4)
#define TST_IDX    512

// legacy f32-fallback layout (round-3/4, proven)
#define L_HX     1024
#define L_HHIST  5120
#define L_PREDS  826368
#define F_PMAX 1646592
#define F_PSUM 1906592
#define F_PARG 2166592
#define F_LSE  2426592

// ---- LDS sizes ----
#define GEMM_SMEM  12800                         // f32 tile: Wt[16][132]+Xt[16][68]
#define CHAIN_SMEM ((16 * NSTEPP + 2048 + 64) * 4)   // gxl f32 + h dbuf + GS
#define JOIN_SMEM  (65536 + 128)
// f32 fallback LDS layout (floats)
#define S_XH   0
#define S_GS   3072
#define S_C4   3088
#define S_TOK  3264
#define S_RED  4066
#define S_AMAX 4082
#define SMEM_FLOATS_F32 4352
#define SMEM_BYTES_F32 (SMEM_FLOATS_F32 * 4)

// ======================= shared helpers =======================

__device__ __forceinline__ float dot4(float4 a, float4 b, float acc) {
  acc = fmaf(a.x, b.x, acc); acc = fmaf(a.y, b.y, acc);
  acc = fmaf(a.z, b.z, acc); acc = fmaf(a.w, b.w, acc);
  return acc;
}
__device__ __forceinline__ float sigmf(float x) { return 1.f / (1.f + expf(-x)); }
__device__ __forceinline__ float sigm_fast(float x) { return 1.f / (1.f + __expf(-x)); }
__device__ __forceinline__ float tanh_fast(float x) {
  float e = __expf(2.f * x);
  return 1.f - 2.f / (e + 1.f);
}

__device__ __forceinline__ void combine3(float& m, float& s, int& am,
                                         float om, float os, int oa) {
  float mm = fmaxf(m, om);
  s = s * __expf(m - mm) + os * __expf(om - mm);
  if (om > m || (om == m && oa < am)) am = oa;
  m = mm;
}

__device__ __forceinline__ void gload16(const void* g, void* l) {
  __builtin_amdgcn_global_load_lds(
      (const __attribute__((address_space(1))) unsigned int*)g,
      (__attribute__((address_space(3))) unsigned int*)l, 16, 0, 0);
}

__device__ __forceinline__ float ld_coh(const float* p) {
  return __hip_atomic_load((const float*)p, __ATOMIC_RELAXED, __HIP_MEMORY_SCOPE_AGENT);
}

// light barrier: flag-array + release word (data must travel via sc1 atomics)
__device__ __forceinline__ void light_barrier(unsigned* flags, unsigned& ep) {
  unsigned* arrive  = flags;
  unsigned* release = flags + 256;
  __builtin_amdgcn_s_waitcnt(0);
  __syncthreads();
  if (blockIdx.x == 0) {
    int tid = threadIdx.x;
    if (tid > 0 && tid < NWG) {
      while (__hip_atomic_load(&arrive[tid], __ATOMIC_RELAXED, __HIP_MEMORY_SCOPE_AGENT) != ep) {}
    }
    __syncthreads();
    if (tid == 0)
      __hip_atomic_store(release, ep, __ATOMIC_RELAXED, __HIP_MEMORY_SCOPE_AGENT);
  } else {
    if (threadIdx.x == 0) {
      __hip_atomic_store(&arrive[blockIdx.x], ep, __ATOMIC_RELAXED, __HIP_MEMORY_SCOPE_AGENT);
      while (__hip_atomic_load(release, __ATOMIC_RELAXED, __HIP_MEMORY_SCOPE_AGENT) != ep) {}
    }
    __syncthreads();
  }
  asm volatile("" ::: "memory");
  ep++;
}

// heavy barrier: full fence (wbl2+inv) for plain-store handoffs
__device__ __forceinline__ void heavy_barrier(unsigned* flags) {
  unsigned* bar = flags + 257;
  __syncthreads();
  if (threadIdx.x == 0) {
    __threadfence();
    unsigned g = __hip_atomic_load(&bar[1], __ATOMIC_RELAXED, __HIP_MEMORY_SCOPE_AGENT);
    unsigned v = __hip_atomic_fetch_add(&bar[0], 1u, __ATOMIC_RELAXED, __HIP_MEMORY_SCOPE_AGENT);
    if (v == (unsigned)(NWG - 1)) {
      __hip_atomic_store(&bar[0], 0u, __ATOMIC_RELAXED, __HIP_MEMORY_SCOPE_AGENT);
      __hip_atomic_store(&bar[1], g + 1u, __ATOMIC_RELEASE, __HIP_MEMORY_SCOPE_AGENT);
    } else {
      while (__hip_atomic_load(&bar[1], __ATOMIC_RELAXED, __HIP_MEMORY_SCOPE_AGENT) == g)
        __builtin_amdgcn_s_sleep(1);
    }
    __threadfence();
  }
  __syncthreads();
}

// Xbf rows: dst[j] = bf16(relu(enc[t0+j] + preds[pi])), j in [0,K)
__device__ void xbf_fill(const float* enc, const float* preds, __bf16* dst,
                         int t0, int K, int pi0, int g0, int gs) {
  int total = K << 8;
  for (int q = g0; q < total; q += gs) {
    int j = q >> 8, seg = q & 255;
    int pi = (pi0 < 0) ? NPH : pi0 + j;
    float4 e = ((const float4*)(enc + (size_t)(t0 + j) * 1024))[seg];
    float4 p = ((const float4*)(preds + (size_t)pi * 1024))[seg];
    bf16x4 r;
    r[0] = (__bf16)fmaxf(e.x + p.x, 0.f);
    r[1] = (__bf16)fmaxf(e.y + p.y, 0.f);
    r[2] = (__bf16)fmaxf(e.z + p.z, 0.f);
    r[3] = (__bf16)fmaxf(e.w + p.w, 0.f);
    *(bf16x4*)(dst + (size_t)j * 1024 + (seg << 2)) = r;
  }
}

// MFMA joiner: 128v x 128j tiles, 8 waves, mfma_f32_32x32x16_bf16, fused partials
__device__ void joiner_tiles(const __bf16* W16, const __bf16* xrows, const float* bj,
                             float* out_align, float* pmax, float* psum, int* parg,
                             char* smc, int t0, int K, int tile0, int tstride) {
  const int tid = threadIdx.x;
  const int wid = tid >> 6, lane = tid & 63;
  const int wj = wid & 3, wv = wid >> 2;
  const int l31 = lane & 31, lhi = lane >> 5;
  const int jt_n = (K + 127) >> 7;
  const int ntiles = jt_n * NVT;

  for (int tile = tile0; tile < ntiles; tile += tstride) {
    const int vt = tile % NVT, jt = tile / NVT;
    const int v0 = vt << 7, j0 = jt << 7;
    f32x16 acc0, acc1;
    #pragma unroll
    for (int i = 0; i < 16; ++i) { acc0[i] = 0.f; acc1[i] = 0.f; }

    auto stage = [&](int db, int kb) {
      char* wb = smc + db * 32768;
      char* xb = wb + 16384;
      #pragma unroll
      for (int p = 0; p < 2; ++p) {
        int sbase = p * 512 + wid * 64;
        int s = sbase + lane;
        int ks = s >> 7, r = s & 127;
        gload16(W16 + (size_t)(v0 + r) * 1024 + kb + ks * 8, wb + sbase * 16);
        gload16(xrows + (size_t)(j0 + r) * 1024 + kb + ks * 8, xb + sbase * 16);
      }
    };

    stage(0, 0);
    __syncthreads();
    int db = 0;
    for (int kb16 = 0; kb16 < 16; ++kb16) {
      if (kb16 < 15) stage(db ^ 1, (kb16 + 1) << 6);
      const char* wb = smc + db * 32768;
      const char* xb = wb + 16384;
      #pragma unroll
      for (int k16 = 0; k16 < 4; ++k16) {
        int ks = k16 * 2 + lhi;
        bf16x8 a  = *(const bf16x8*)(xb + ((ks << 7) + (wj << 5) + l31) * 16);
        bf16x8 b0 = *(const bf16x8*)(wb + ((ks << 7) + (wv << 6) + l31) * 16);
        bf16x8 b1 = *(const bf16x8*)(wb + ((ks << 7) + (wv << 6) + 32 + l31) * 16);
        acc0 = __builtin_amdgcn_mfma_f32_32x32x16_bf16(a, b0, acc0, 0, 0, 0);
        acc1 = __builtin_amdgcn_mfma_f32_32x32x16_bf16(a, b1, acc1, 0, 0, 0);
      }
      __syncthreads();
      db ^= 1;
    }

    const int v_0 = v0 + (wv << 6) + l31;
    const int v_1 = v_0 + 32;
    const float bj0 = (v_0 < VD) ? bj[v_0] : 0.f;
    const float bj1 = (v_1 < VD) ? bj[v_1] : 0.f;
    const int jbase = j0 + (wj << 5) + 4 * lhi;
    const bool npok = (v0 + (wv << 6)) < VD;
    const int np = (v0 >> 6) + wv;
    #pragma unroll
    for (int reg = 0; reg < 16; ++reg) {
      int j = jbase + (reg & 3) + 8 * (reg >> 2);
      bool jok = j < K;
      float lg0 = acc0[reg] + bj0;
      float lg1 = acc1[reg] + bj1;
      if (jok) {
        size_t ro = (size_t)(t0 + j) * VD;
        if (v_0 < VD) out_align[ro + v_0] = lg0;
        if (v_1 < VD) out_align[ro + v_1] = lg1;
      }
      float l0 = (v_0 < VD) ? lg0 : -1e30f;
      float l1 = (v_1 < VD) ? lg1 : -1e30f;
      float m = fmaxf(l0, l1);
      float ss = 0.f;
      if (v_0 < VD) ss += __expf(l0 - m);
      if (v_1 < VD) ss += __expf(l1 - m);
      int am = (l1 > l0) ? v_1 : v_0;
      #pragma unroll
      for (int msk = 1; msk <= 16; msk <<= 1) {
        float om = __shfl_xor(m, msk, 64);
        float os = __shfl_xor(ss, msk, 64);
        int oa = __shfl_xor(am, msk, 64);
        float mm = fmaxf(m, om);
        ss = ss * __expf(m - mm) + os * __expf(om - mm);
        if (om > m || (om == m && oa < am)) am = oa;
        m = mm;
      }
      if (l31 == 0 && jok && npok) {
        size_t pb = (size_t)(t0 + j) * NP + np;
        __hip_atomic_store(&pmax[pb], m, __ATOMIC_RELAXED, __HIP_MEMORY_SCOPE_AGENT);
        __hip_atomic_store(&psum[pb], ss, __ATOMIC_RELAXED, __HIP_MEMORY_SCOPE_AGENT);
        __hip_atomic_store(&parg[pb], am, __ATOMIC_RELAXED, __HIP_MEMORY_SCOPE_AGENT);
      }
    }
  }
}

__device__ __forceinline__ void merge_row129(const float* pmax, const float* psum,
                                             const int* parg, int row, int lane,
                                             float& m, float& s, int& am) {
  size_t b = (size_t)row * NP;
  m = ld_coh(pmax + b + lane);
  s = ld_coh(psum + b + lane);
  am = __hip_atomic_load(&parg[b + lane], __ATOMIC_RELAXED, __HIP_MEMORY_SCOPE_AGENT);
  {
    int i2 = lane + 64;
    float om = ld_coh(pmax + b + i2);
    float os = ld_coh(psum + b + i2);
    int oa = __hip_atomic_load(&parg[b + i2], __ATOMIC_RELAXED, __HIP_MEMORY_SCOPE_AGENT);
    combine3(m, s, am, om, os, oa);
  }
  if (lane == 0) {
    float om = ld_coh(pmax + b + 128);
    float os = ld_coh(psum + b + 128);
    int oa = __hip_atomic_load(&parg[b + 128], __ATOMIC_RELAXED, __HIP_MEMORY_SCOPE_AGENT);
    combine3(m, s, am, om, os, oa);
  }
  #pragma unroll
  for (int msk = 32; msk; msk >>= 1) {
    float om = __shfl_xor(m, msk, 64);
    float os = __shfl_xor(s, msk, 64);
    int oa = __shfl_xor(am, msk, 64);
    combine3(m, s, am, om, os, oa);
  }
}

// ======================= K1a: W_join -> bf16 =======================
__global__ __launch_bounds__(512) void wconv_kernel(const float* __restrict__ Wjoin,
                                                    float* wsf) {
  __bf16* w16 = (__bf16*)(wsf + WSF_W16);
  int g0 = blockIdx.x * 512 + threadIdx.x;
  int gs = gridDim.x * 512;
  for (int q = g0; q < VD * 256; q += gs) {
    int v = q >> 8, seg = q & 255;
    float4 w4 = ((const float4*)(Wjoin + (size_t)v * 1024))[seg];
    bf16x4 r;
    r[0] = (__bf16)w4.x; r[1] = (__bf16)w4.y; r[2] = (__bf16)w4.z; r[3] = (__bf16)w4.w;
    *(bf16x4*)(w16 + (size_t)v * 1024 + (seg << 2)) = r;
  }
}

// ======================= K1b: gxT[gr][s] = Wih@emb[tok_s] + bl (f32) ========
__global__ __launch_bounds__(512) void gx_kernel(
    const float* __restrict__ Wih, const float* __restrict__ emb,
    const float* __restrict__ bl, const int* __restrict__ phon, float* wsf) {
  extern __shared__ float sm[];
  float* Wt = sm;          // [16][132]
  float* Xt = sm + 2112;   // [16][68]
  float* gxT = wsf + WSF_GXT;
  const int tid = threadIdx.x;
  const int tx = tid & 31, ty = tid >> 5;
  int ntiles = 32 * 13;
  for (int tile = blockIdx.x; tile < ntiles; tile += gridDim.x) {
    int vt = tile & 31, jt = tile >> 5;
    int v0 = vt * 128, j0 = jt * 64;
    float acc[4][4];
    #pragma unroll
    for (int a = 0; a < 4; ++a)
      #pragma unroll
      for (int q = 0; q < 4; ++q) acc[a][q] = 0.f;
    for (int kk = 0; kk < DEMB; kk += 16) {
      {
        int r = tid >> 2, seg = tid & 3;
        float4 wv = ((const float4*)(Wih + (size_t)(v0 + r) * DEMB + kk))[seg];
        Wt[(seg * 4 + 0) * 132 + r] = wv.x;
        Wt[(seg * 4 + 1) * 132 + r] = wv.y;
        Wt[(seg * 4 + 2) * 132 + r] = wv.z;
        Wt[(seg * 4 + 3) * 132 + r] = wv.w;
      }
      if (tid < 256) {
        int r = tid >> 2, seg = tid & 3;
        int j = j0 + r;
        float4 xv = make_float4(0.f, 0.f, 0.f, 0.f);
        if (j < NSTEP) {
          int tok = (j < 2) ? BLANK : phon[j - 2];
          xv = ((const float4*)(emb + (size_t)tok * DEMB + kk))[seg];
        }
        Xt[(seg * 4 + 0) * 68 + r] = xv.x;
        Xt[(seg * 4 + 1) * 68 + r] = xv.y;
        Xt[(seg * 4 + 2) * 68 + r] = xv.z;
        Xt[(seg * 4 + 3) * 68 + r] = xv.w;
      }
      __syncthreads();
      #pragma unroll
      for (int k = 0; k < 16; ++k) {
        float4 a = *(const float4*)(Wt + k * 132 + (tx << 2));
        float4 bq = *(const float4*)(Xt + k * 68 + (ty << 2));
        acc[0][0] = fmaf(a.x, bq.x, acc[0][0]); acc[1][0] = fmaf(a.y, bq.x, acc[1][0]);
        acc[2][0] = fmaf(a.z, bq.x, acc[2][0]); acc[3][0] = fmaf(a.w, bq.x, acc[3][0]);
        acc[0][1] = fmaf(a.x, bq.y, acc[0][1]); acc[1][1] = fmaf(a.y, bq.y, acc[1][1]);
        acc[2][1] = fmaf(a.z, bq.y, acc[2][1]); acc[3][1] = fmaf(a.w, bq.y, acc[3][1]);
        acc[0][2] = fmaf(a.x, bq.z, acc[0][2]); acc[1][2] = fmaf(a.y, bq.z, acc[1][2]);
        acc[2][2] = fmaf(a.z, bq.z, acc[2][2]); acc[3][2] = fmaf(a.w, bq.z, acc[3][2]);
        acc[0][3] = fmaf(a.x, bq.w, acc[0][3]); acc[1][3] = fmaf(a.y, bq.w, acc[1][3]);
        acc[2][3] = fmaf(a.z, bq.w, acc[2][3]); acc[3][3] = fmaf(a.w, bq.w, acc[3][3]);
      }
      __syncthreads();
    }
    int vb = v0 + (tx << 2), jb0 = j0 + (ty << 2);
    #pragma unroll
    for (int jj = 0; jj < 4; ++jj) {
      int j = jb0 + jj;
      if (j >= NSTEP) continue;
      #pragma unroll
      for (int q = 0; q < 4; ++q)
        gxT[(size_t)(vb + q) * NSTEPP + j] = acc[q][jj] + bl[vb + q];
    }
  }
}

// ======================= K2: sequential LSTM chain (coop, 256 WGs) ==========
// R4/R8-proven protocol: tagged {tag|f32 h} u64 per cell, parity double buffer,
// dual-load poll with no sleep, critical hx store issued before hhist store.
__global__ __launch_bounds__(NTHR) void chain_kernel(const float* __restrict__ Whh,
                                                     float* wsf) {
  extern __shared__ float sm[];
  float* gxl = sm;                  // [16][802] f32
  float* hb  = sm + 16 * NSTEPP;    // [2][1024]
  float* GS  = hb + 2048;           // [16]
  const int tid = threadIdx.x;
  const int w = tid >> 6, l = tid & 63;
  const int b = blockIdx.x;
  const float* gxT = wsf + WSF_GXT;
  float* hhist = wsf + WSF_HHIST;
  unsigned long long* hx = (unsigned long long*)(wsf + WSF_HX);

  // register-resident Whh slices: wave w rows rr0=2w, rr1=2w+1 (rr = q*4+j)
  float4 W0[4], W1[4];
  {
    int rr0 = 2 * w, rr1 = 2 * w + 1;
    int gr0 = ((rr0 >> 2) << 10) + 4 * b + (rr0 & 3);
    int gr1 = ((rr1 >> 2) << 10) + 4 * b + (rr1 & 3);
    const float4* h0 = (const float4*)(Whh + (size_t)gr0 * HD);
    const float4* h1 = (const float4*)(Whh + (size_t)gr1 * HD);
    #pragma unroll
    for (int i = 0; i < 4; ++i) { W0[i] = h0[l + 64 * i]; W1[i] = h1[l + 64 * i]; }
  }
  // LDS-preload the gx slice for this WG's 16 rows (all 802 steps)
  for (int rr = 0; rr < 16; ++rr) {
    int gr = ((rr >> 2) << 10) + 4 * b + (rr & 3);
    for (int s = tid; s < NSTEP; s += NTHR)
      gxl[rr * NSTEPP + s] = gxT[(size_t)gr * NSTEPP + s];
  }
  for (int i = tid; i < 1024; i += NTHR) hb[i] = 0.f;   // h(0) = 0 in buffer 0
  __syncthreads();

  float c_reg = 0.f;
  for (int s = 0; s < NSTEP; ++s) {
    int p = s & 1;
    const float4* h4 = (const float4*)(hb + p * 1024);
    float a0 = 0.f, a1 = 0.f;
    #pragma unroll
    for (int i = 0; i < 4; ++i) {
      float4 hv = h4[l + 64 * i];
      a0 = dot4(W0[i], hv, a0);
      a1 = dot4(W1[i], hv, a1);
    }
    #pragma unroll
    for (int m = 32; m; m >>= 1) {
      a0 += __shfl_xor(a0, m, 64);
      a1 += __shfl_xor(a1, m, 64);
    }
    if (l == 0) { GS[2 * w] = a0; GS[2 * w + 1] = a1; }
    __syncthreads();
    if (tid < 4) {
      int j = tid;
      float gi = GS[j]      + gxl[j * NSTEPP + s];
      float gf = GS[4 + j]  + gxl[(4 + j) * NSTEPP + s];
      float gg = GS[8 + j]  + gxl[(8 + j) * NSTEPP + s];
      float go = GS[12 + j] + gxl[(12 + j) * NSTEPP + s];
      float c2 = sigm_fast(gf) * c_reg + sigm_fast(gi) * tanh_fast(gg);
      float h2 = sigm_fast(go) * tanh_fast(c2);
      c_reg = c2;
      int cell = 4 * b + j;
      // critical exchange store FIRST (consumers are polling this)
      unsigned long long pk = ((unsigned long long)(unsigned)(s + 1) << 32)
                            | (unsigned long long)__float_as_uint(h2);
      __hip_atomic_store(&hx[(p ^ 1) * 1024 + cell], pk,
                         __ATOMIC_RELAXED, __HIP_MEMORY_SCOPE_AGENT);
      hhist[(size_t)s * HD + cell] = h2;   // non-critical history (kernel-boundary flush)
    }
    if (s + 1 < NSTEP) {
      unsigned tg = (unsigned)(s + 1);
      const unsigned long long* src = hx + (p ^ 1) * 1024;
      unsigned long long v0, v1;
      do {  // both loads in flight per retry, no sleep
        v0 = __hip_atomic_load(&src[2 * tid],     __ATOMIC_RELAXED, __HIP_MEMORY_SCOPE_AGENT);
        v1 = __hip_atomic_load(&src[2 * tid + 1], __ATOMIC_RELAXED, __HIP_MEMORY_SCOPE_AGENT);
      } while ((unsigned)(v0 >> 32) != tg || (unsigned)(v1 >> 32) != tg);
      float* dst = hb + (p ^ 1) * 1024 + 2 * tid;
      dst[0] = __uint_as_float((unsigned)v0);
      dst[1] = __uint_as_float((unsigned)v1);
    }
    __syncthreads();
  }
}

// ======================= K2b: preds = W_pred @ hhist + bp ===================
__global__ __launch_bounds__(512) void preds_kernel(
    const float* __restrict__ Wpred, const float* __restrict__ bp, float* wsf) {
  extern __shared__ float sm[];
  float* Wt = sm;
  float* Xt = sm + 2112;
  const float* hhist = wsf + WSF_HHIST;
  float* preds = wsf + WSF_PREDS;
  const int tid = threadIdx.x;
  const int tx = tid & 31, ty = tid >> 5;
  int ntiles = 8 * 13;
  for (int tile = blockIdx.x; tile < ntiles; tile += gridDim.x) {
    int vt = tile & 7, jt = tile >> 3;
    int v0 = vt * 128, j0 = jt * 64;
    float acc[4][4];
    #pragma unroll
    for (int a = 0; a < 4; ++a)
      #pragma unroll
      for (int q = 0; q < 4; ++q) acc[a][q] = 0.f;
    for (int kk = 0; kk < 1024; kk += 16) {
      {
        int r = tid >> 2, seg = tid & 3;
        float4 wv = ((const float4*)(Wpred + (size_t)(v0 + r) * HD + kk))[seg];
        Wt[(seg * 4 + 0) * 132 + r] = wv.x;
        Wt[(seg * 4 + 1) * 132 + r] = wv.y;
        Wt[(seg * 4 + 2) * 132 + r] = wv.z;
        Wt[(seg * 4 + 3) * 132 + r] = wv.w;
      }
      if (tid < 256) {
        int r = tid >> 2, seg = tid & 3;
        int j = j0 + r;
        float4 xv = make_float4(0.f, 0.f, 0.f, 0.f);
        if (j <= NPH) xv = ((const float4*)(hhist + (size_t)(j + 1) * HD + kk))[seg];
        Xt[(seg * 4 + 0) * 68 + r] = xv.x;
        Xt[(seg * 4 + 1) * 68 + r] = xv.y;
        Xt[(seg * 4 + 2) * 68 + r] = xv.z;
        Xt[(seg * 4 + 3) * 68 + r] = xv.w;
      }
      __syncthreads();
      #pragma unroll
      for (int k = 0; k < 16; ++k) {
        float4 a = *(const float4*)(Wt + k * 132 + (tx << 2));
        float4 bq = *(const float4*)(Xt + k * 68 + (ty << 2));
        acc[0][0] = fmaf(a.x, bq.x, acc[0][0]); acc[1][0] = fmaf(a.y, bq.x, acc[1][0]);
        acc[2][0] = fmaf(a.z, bq.x, acc[2][0]); acc[3][0] = fmaf(a.w, bq.x, acc[3][0]);
        acc[0][1] = fmaf(a.x, bq.y, acc[0][1]); acc[1][1] = fmaf(a.y, bq.y, acc[1][1]);
        acc[2][1] = fmaf(a.z, bq.y, acc[2][1]); acc[3][1] = fmaf(a.w, bq.y, acc[3][1]);
        acc[0][2] = fmaf(a.x, bq.z, acc[0][2]); acc[1][2] = fmaf(a.y, bq.z, acc[1][2]);
        acc[2][2] = fmaf(a.z, bq.z, acc[2][2]); acc[3][2] = fmaf(a.w, bq.z, acc[3][2]);
        acc[0][3] = fmaf(a.x, bq.w, acc[0][3]); acc[1][3] = fmaf(a.y, bq.w, acc[1][3]);
        acc[2][3] = fmaf(a.z, bq.w, acc[2][3]); acc[3][3] = fmaf(a.w, bq.w, acc[3][3]);
      }
      __syncthreads();
    }
    int vb = v0 + (tx << 2), jb0 = j0 + (ty << 2);
    #pragma unroll
    for (int jj = 0; jj < 4; ++jj) {
      int j = jb0 + jj;
      if (j > NPH) continue;
      #pragma unroll
      for (int q = 0; q < 4; ++q)
        preds[(size_t)j * 1024 + vb + q] = acc[q][jj] + bp[vb + q];
    }
  }
}

// ======================= K2c: speculative-chunk xbf =========================
__global__ void xspec_kernel(const float* __restrict__ enc, float* wsf) {
  xbf_fill(enc, wsf + WSF_PREDS, (__bf16*)(wsf + WSF_XBF), 0, CHUNK_M, 0,
           blockIdx.x * blockDim.x + threadIdx.x, gridDim.x * blockDim.x);
}

// ======================= K3a: speculative joiner (plain) ====================
__global__ __launch_bounds__(NTHR) void joinspec_kernel(const float* __restrict__ bj,
                                                        float* out, float* wsf) {
  extern __shared__ float sm[];
  joiner_tiles((__bf16*)(wsf + WSF_W16), (__bf16*)(wsf + WSF_XBF), bj, out,
               wsf + WSF_PMAX, wsf + WSF_PSUM, (int*)(wsf + WSF_PARG),
               (char*)sm, 0, CHUNK_M, blockIdx.x, gridDim.x);
}

// ======================= K3b: decode loop (coop) ============================
__global__ __launch_bounds__(NTHR) void decode_coop(
    const float* enc, const float* bj, const int* phon, float* out, float* wsf) {
  extern __shared__ float sm[];
  char* smc = (char*)sm;
  unsigned* flags = (unsigned*)wsf;
  float* preds = wsf + WSF_PREDS;
  float* pmax = wsf + WSF_PMAX;
  float* psum = wsf + WSF_PSUM;
  int* parg = (int*)(wsf + WSF_PARG);
  float* lse = wsf + WSF_LSE;
  int* amaxws = (int*)(wsf + WSF_AMAX);
  __bf16* xbf = (__bf16*)(wsf + WSF_XBF);
  __bf16* w16 = (__bf16*)(wsf + WSF_W16);
  float* out_pred  = out + (size_t)TT * VD;
  float* out_valid = out + (size_t)TT * VD + TT;

  const int tid = threadIdx.x;
  const int wid = tid >> 6, lane = tid & 63;
  unsigned ep = 1;
  int t = 0, tp = 0, iter = 0;

  while (t < TT && tp < NPH) {
    int K = CHUNK_M;
    if (TT - t < K) K = TT - t;
    if (NPH - tp < K) K = NPH - tp;
    if (iter > 0) {   // rare rollback: recompute chunk with corrected preds
      heavy_barrier(flags);
      xbf_fill(enc, preds, xbf, t, K, tp, blockIdx.x * NTHR + tid, gridDim.x * NTHR);
      heavy_barrier(flags);
      joiner_tiles(w16, xbf, bj, out, pmax, psum, parg, smc, t, K,
                   blockIdx.x, gridDim.x);
    }
    light_barrier(flags, ep);
    for (int j = blockIdx.x * 8 + wid; j < K; j += gridDim.x * 8) {
      float m, s; int am;
      merge_row129(pmax, psum, parg, t + j, lane, m, s, am);
      if (lane == 0) {
        __hip_atomic_store(&amaxws[j], am, __ATOMIC_RELAXED, __HIP_MEMORY_SCOPE_AGENT);
        lse[t + j] = m + logf(s);
      }
    }
    light_barrier(flags, ep);
    int cand = K;
    for (int idx = tid; idx < K; idx += NTHR) {
      int a = __hip_atomic_load(&amaxws[idx], __ATOMIC_RELAXED, __HIP_MEMORY_SCOPE_AGENT);
      if (a == BLANK && idx < cand) cand = idx;
    }
    #pragma unroll
    for (int msk = 32; msk; msk >>= 1) cand = min(cand, __shfl_xor(cand, msk, 64));
    int* red = (int*)(smc + 65536);
    if (lane == 0) red[wid] = cand;
    __syncthreads();
    if (tid == 0) {
      int mn = red[0];
      for (int w2 = 1; w2 < 8; ++w2) mn = min(mn, red[w2]);
      red[8] = mn;
    }
    __syncthreads();
    int jb = red[8];
    __syncthreads();
    int nacc = (jb < K) ? jb + 1 : K;
    int nadv = (jb < K) ? jb : K;
    if (blockIdx.x == 0) {
      for (int j = tid; j < nacc; j += NTHR) {
        out_pred[t + j] = (j == jb) ? (float)BLANK : (float)phon[tp + j];
        out_valid[t + j] = 1.f;
      }
    }
    t += nacc; tp += nadv; ++iter;
  }

  if (t < TT) {
    xbf_fill(enc, preds, xbf + (size_t)(t - 800) * 1024, t, TT - t, -1,
             blockIdx.x * NTHR + tid, gridDim.x * NTHR);
  }
  if (blockIdx.x == 0 && tid == 0) ((int*)wsf)[TST_IDX] = t;
}

// ======================= K4: tail joiner (plain) ============================
__global__ __launch_bounds__(NTHR) void jointail_kernel(const float* __restrict__ bj,
                                                        float* out, float* wsf) {
  extern __shared__ float sm[];
  int t = ((const int*)wsf)[TST_IDX];
  if (t >= TT) return;
  joiner_tiles((__bf16*)(wsf + WSF_W16),
               (__bf16*)(wsf + WSF_XBF) + (size_t)(t - 800) * 1024, bj, out,
               wsf + WSF_PMAX, wsf + WSF_PSUM, (int*)(wsf + WSF_PARG),
               (char*)sm, t, TT - t, blockIdx.x, gridDim.x);
}

// ======================= K5: tail merge -> lse, pred/valid ==================
__global__ __launch_bounds__(NTHR) void mergetail_kernel(float* out, float* wsf) {
  int t = ((const int*)wsf)[TST_IDX];
  float* lse = wsf + WSF_LSE;
  float* out_pred  = out + (size_t)TT * VD;
  float* out_valid = out + (size_t)TT * VD + TT;
  const int wid = threadIdx.x >> 6, lane = threadIdx.x & 63;
  for (int row = t + blockIdx.x * 8 + wid; row < TT; row += gridDim.x * 8) {
    float m, s; int am;
    merge_row129(wsf + WSF_PMAX, wsf + WSF_PSUM, (const int*)(wsf + WSF_PARG),
                 row, lane, m, s, am);
    if (lane == 0) {
      lse[row] = m + logf(s);
      out_pred[row] = (float)BLANK;
      out_valid[row] = 0.f;
    }
  }
}

// ======================= K6: logp = logits - lse (float4) ===================
__global__ __launch_bounds__(256) void sub_kernel(float* out, const float* wsf) {
  const float* lse = wsf + WSF_LSE;
  for (int row = blockIdx.x; row < TT; row += gridDim.x) {
    float l = lse[row];
    float4* p4 = (float4*)(out + (size_t)row * VD);
    #pragma unroll
    for (int k = 0; k < 8; ++k) {
      int i = threadIdx.x + k * 256;   // 2048 float4 cover 8192 floats
      float4 v = p4[i];
      v.x -= l; v.y -= l; v.z -= l; v.w -= l;
      p4[i] = v;
    }
    if (threadIdx.x == 0) out[(size_t)row * VD + 8192] -= l;
  }
}

// ======================= f32 fallback (round-3/4, proven) ===================
struct Ctx {
  const float *enc, *emb, *Wih, *Whh, *bl, *Wpred, *bp, *Wjoin, *bj;
  const int* phon;
  unsigned long long* hx;
  float *hhist, *preds, *pmax, *psum, *lse;
  int* parg;
  unsigned* flags;
  float *out_align, *out_pred, *out_valid;
};

__device__ void chain_all_legacy(const Ctx& C, float* sm) {
  const int tid = threadIdx.x;
  const int w = tid >> 6, l = tid & 63;
  const int b = blockIdx.x;
  int* tok_sm = (int*)(sm + S_TOK);
  for (int s = tid; s < NSTEP; s += NTHR)
    tok_sm[s] = (s < 2) ? BLANK : C.phon[s - 2];
  float4 W0[6], W1[6];
  {
    int rr0 = 2 * w, rr1 = 2 * w + 1;
    int gr0 = ((rr0 >> 2) << 10) + 4 * b + (rr0 & 3);
    int gr1 = ((rr1 >> 2) << 10) + 4 * b + (rr1 & 3);
    const float4* ih0 = (const float4*)(C.Wih + (size_t)gr0 * DEMB);
    const float4* hh0 = (const float4*)(C.Whh + (size_t)gr0 * HD);
    const float4* ih1 = (const float4*)(C.Wih + (size_t)gr1 * DEMB);
    const float4* hh1 = (const float4*)(C.Whh + (size_t)gr1 * HD);
    W0[0] = ih0[l];       W0[1] = ih0[64 + l];
    W0[2] = hh0[l];       W0[3] = hh0[64 + l];
    W0[4] = hh0[128 + l]; W0[5] = hh0[192 + l];
    W1[0] = ih1[l];       W1[1] = ih1[64 + l];
    W1[2] = hh1[l];       W1[3] = hh1[64 + l];
    W1[4] = hh1[128 + l]; W1[5] = hh1[192 + l];
  }
  float bi = 0.f, bf = 0.f, bg = 0.f, bo = 0.f;
  if (tid < 4) {
    bi = C.bl[4 * b + tid];
    bf = C.bl[1024 + 4 * b + tid];
    bg = C.bl[2048 + 4 * b + tid];
    bo = C.bl[3072 + 4 * b + tid];
    sm[S_C4 + tid] = 0.f;
  }
  for (int i = tid; i < 1536; i += NTHR) sm[S_XH + i] = 0.f;
  if (tid < 512) sm[S_XH + tid] = C.emb[(size_t)BLANK * DEMB + tid];
  __syncthreads();
  unsigned long long* hx = C.hx;
  for (int s = 0; s < NSTEP; ++s) {
    int p = s & 1;
    const float4* xh4 = (const float4*)(sm + S_XH + p * 1536);
    float a0 = 0.f, a1 = 0.f;
    #pragma unroll
    for (int i = 0; i < 6; ++i) {
      float4 v = xh4[i * 64 + l];
      a0 = dot4(W0[i], v, a0);
      a1 = dot4(W1[i], v, a1);
    }
    #pragma unroll
    for (int m = 32; m; m >>= 1) {
      a0 += __shfl_xor(a0, m, 64);
      a1 += __shfl_xor(a1, m, 64);
    }
    if (l == 0) { sm[S_GS + 2 * w] = a0; sm[S_GS + 2 * w + 1] = a1; }
    if (s + 1 < NSTEP && tid < 512)
      sm[S_XH + (1 - p) * 1536 + tid] = C.emb[(size_t)tok_sm[s + 1] * DEMB + tid];
    __syncthreads();
    if (tid < 4) {
      int j = tid;
      float gi = sm[S_GS + j]      + bi;
      float gf = sm[S_GS + 4 + j]  + bf;
      float gg = sm[S_GS + 8 + j]  + bg;
      float go = sm[S_GS + 12 + j] + bo;
      float cc = sm[S_C4 + j];
      float c2 = sigmf(gf) * cc + sigmf(gi) * tanhf(gg);
      float h2 = sigmf(go) * tanhf(c2);
      sm[S_C4 + j] = c2;
      int cell = 4 * b + j;
      C.hhist[(size_t)s * HD + cell] = h2;
      unsigned long long pk = ((unsigned long long)(unsigned)(s + 1) << 32)
                            | (unsigned long long)__float_as_uint(h2);
      __hip_atomic_store(&hx[(1 - p) * 1024 + cell], pk,
                         __ATOMIC_RELAXED, __HIP_MEMORY_SCOPE_AGENT);
    }
    if (s + 1 < NSTEP) {
      unsigned tg = (unsigned)(s + 1);
      #pragma unroll
      for (int kq = 0; kq < 2; ++kq) {
        int k = tid + kq * 512;
        unsigned long long v;
        do {
          v = __hip_atomic_load(&hx[(1 - p) * 1024 + k],
                                __ATOMIC_RELAXED, __HIP_MEMORY_SCOPE_AGENT);
        } while ((unsigned)(v >> 32) != tg);
        sm[S_XH + (1 - p) * 1536 + 512 + k] = __uint_as_float((unsigned)v);
      }
    }
    __syncthreads();
  }
}

__device__ void preds_gemm_legacy(const Ctx& C, float* sm) {
  float* Wt = sm;
  float* Xt = sm + 2112;
  const int tid = threadIdx.x;
  const int tx = tid & 31, ty = tid >> 5;
  int ntiles = 8 * 13;
  for (int tile = blockIdx.x; tile < ntiles; tile += NWG) {
    int vt = tile & 7, jt = tile >> 3;
    int v0 = vt * 128, j0 = jt * 64;
    float acc[4][4];
    #pragma unroll
    for (int a = 0; a < 4; ++a)
      #pragma unroll
      for (int q = 0; q < 4; ++q) acc[a][q] = 0.f;
    for (int kk = 0; kk < 1024; kk += 16) {
      {
        int r = tid >> 2, seg = tid & 3;
        float4 wv = ((const float4*)(C.Wpred + (size_t)(v0 + r) * HD + kk))[seg];
        Wt[(seg * 4 + 0) * 132 + r] = wv.x;
        Wt[(seg * 4 + 1) * 132 + r] = wv.y;
        Wt[(seg * 4 + 2) * 132 + r] = wv.z;
        Wt[(seg * 4 + 3) * 132 + r] = wv.w;
      }
      if (tid < 256) {
        int r = tid >> 2, seg = tid & 3;
        int j = j0 + r;
        float4 xv = make_float4(0.f, 0.f, 0.f, 0.f);
        if (j <= NPH) xv = ((const float4*)(C.hhist + (size_t)(j + 1) * HD + kk))[seg];
        Xt[(seg * 4 + 0) * 68 + r] = xv.x;
        Xt[(seg * 4 + 1) * 68 + r] = xv.y;
        Xt[(seg * 4 + 2) * 68 + r] = xv.z;
        Xt[(seg * 4 + 3) * 68 + r] = xv.w;
      }
      __syncthreads();
      #pragma unroll
      for (int k = 0; k < 16; ++k) {
        float4 a = *(const float4*)(Wt + k * 132 + (tx << 2));
        float4 bq = *(const float4*)(Xt + k * 68 + (ty << 2));
        acc[0][0] = fmaf(a.x, bq.x, acc[0][0]); acc[1][0] = fmaf(a.y, bq.x, acc[1][0]);
        acc[2][0] = fmaf(a.z, bq.x, acc[2][0]); acc[3][0] = fmaf(a.w, bq.x, acc[3][0]);
        acc[0][1] = fmaf(a.x, bq.y, acc[0][1]); acc[1][1] = fmaf(a.y, bq.y, acc[1][1]);
        acc[2][1] = fmaf(a.z, bq.y, acc[2][1]); acc[3][1] = fmaf(a.w, bq.y, acc[3][1]);
        acc[0][2] = fmaf(a.x, bq.z, acc[0][2]); acc[1][2] = fmaf(a.y, bq.z, acc[1][2]);
        acc[2][2] = fmaf(a.z, bq.z, acc[2][2]); acc[3][2] = fmaf(a.w, bq.z, acc[3][2]);
        acc[0][3] = fmaf(a.x, bq.w, acc[0][3]); acc[1][3] = fmaf(a.y, bq.w, acc[1][3]);
        acc[2][3] = fmaf(a.z, bq.w, acc[2][3]); acc[3][3] = fmaf(a.w, bq.w, acc[3][3]);
      }
      __syncthreads();
    }
    int vb = v0 + (tx << 2), jb0 = j0 + (ty << 2);
    #pragma unroll
    for (int jj = 0; jj < 4; ++jj) {
      int j = jb0 + jj;
      if (j > NPH) continue;
      #pragma unroll
      for (int q = 0; q < 4; ++q)
        C.preds[(size_t)j * 1024 + vb + q] = acc[q][jj] + C.bp[vb + q];
    }
  }
}

__device__ void joiner_gemm_f32(const Ctx& C, float* sm, int t0, int K, int pi0) {
  float* Wt = sm;
  float* Xt = sm + 2112;
  const int tid = threadIdx.x;
  const int tx = tid & 31, ty = tid >> 5;
  int jt_n = (K + 63) >> 6;
  int ntiles = jt_n * NVT;
  for (int tile = blockIdx.x; tile < ntiles; tile += NWG) {
    int vt = tile % NVT, jt = tile / NVT;
    int v0 = vt * 128, j0 = jt * 64;
    float acc[4][4];
    #pragma unroll
    for (int a = 0; a < 4; ++a)
      #pragma unroll
      for (int q = 0; q < 4; ++q) acc[a][q] = 0.f;
    for (int kk = 0; kk < 1024; kk += 16) {
      {
        int r = tid >> 2, seg = tid & 3;
        int v = v0 + r;
        float4 wv = make_float4(0.f, 0.f, 0.f, 0.f);
        if (v < VD) wv = ((const float4*)(C.Wjoin + (size_t)v * 1024 + kk))[seg];
        Wt[(seg * 4 + 0) * 132 + r] = wv.x;
        Wt[(seg * 4 + 1) * 132 + r] = wv.y;
        Wt[(seg * 4 + 2) * 132 + r] = wv.z;
        Wt[(seg * 4 + 3) * 132 + r] = wv.w;
      }
      if (tid < 256) {
        int r = tid >> 2, seg = tid & 3;
        int j = j0 + r;
        float4 xv = make_float4(0.f, 0.f, 0.f, 0.f);
        if (j < K) {
          int pi = (pi0 < 0) ? NPH : (pi0 + j);
          float4 e = ((const float4*)(C.enc + (size_t)(t0 + j) * DENC + kk))[seg];
          float4 pr = ((const float4*)(C.preds + (size_t)pi * 1024 + kk))[seg];
          xv.x = fmaxf(e.x + pr.x, 0.f);
          xv.y = fmaxf(e.y + pr.y, 0.f);
          xv.z = fmaxf(e.z + pr.z, 0.f);
          xv.w = fmaxf(e.w + pr.w, 0.f);
        }
        Xt[(seg * 4 + 0) * 68 + r] = xv.x;
        Xt[(seg * 4 + 1) * 68 + r] = xv.y;
        Xt[(seg * 4 + 2) * 68 + r] = xv.z;
        Xt[(seg * 4 + 3) * 68 + r] = xv.w;
      }
      __syncthreads();
      #pragma unroll
      for (int k = 0; k < 16; ++k) {
        float4 a = *(const float4*)(Wt + k * 132 + (tx << 2));
        float4 bq = *(const float4*)(Xt + k * 68 + (ty << 2));
        acc[0][0] = fmaf(a.x, bq.x, acc[0][0]); acc[1][0] = fmaf(a.y, bq.x, acc[1][0]);
        acc[2][0] = fmaf(a.z, bq.x, acc[2][0]); acc[3][0] = fmaf(a.w, bq.x, acc[3][0]);
        acc[0][1] = fmaf(a.x, bq.y, acc[0][1]); acc[1][1] = fmaf(a.y, bq.y, acc[1][1]);
        acc[2][1] = fmaf(a.z, bq.y, acc[2][1]); acc[3][1] = fmaf(a.w, bq.y, acc[3][1]);
        acc[0][2] = fmaf(a.x, bq.z, acc[0][2]); acc[1][2] = fmaf(a.y, bq.z, acc[1][2]);
        acc[2][2] = fmaf(a.z, bq.z, acc[2][2]); acc[3][2] = fmaf(a.w, bq.z, acc[3][2]);
        acc[0][3] = fmaf(a.x, bq.w, acc[0][3]); acc[1][3] = fmaf(a.y, bq.w, acc[1][3]);
        acc[2][3] = fmaf(a.z, bq.w, acc[2][3]); acc[3][3] = fmaf(a.w, bq.w, acc[3][3]);
      }
      __syncthreads();
    }
    int vb = v0 + (tx << 2);
    int jb0 = j0 + (ty << 2);
    float bjv[4];
    #pragma unroll
    for (int q = 0; q < 4; ++q) bjv[q] = (vb + q < VD) ? C.bj[vb + q] : 0.f;
    #pragma unroll
    for (int jj = 0; jj < 4; ++jj) {
      int j = jb0 + jj;
      if (j >= K) continue;
      size_t ro = (size_t)(t0 + j) * VD;
      float lg[4];
      float m = -1e30f; int am = vb;
      #pragma unroll
      for (int q = 0; q < 4; ++q) {
        int v = vb + q;
        if (v < VD) {
          lg[q] = acc[q][jj] + bjv[q];
          C.out_align[ro + v] = lg[q];
          if (lg[q] > m) { m = lg[q]; am = v; }
        } else lg[q] = -1e30f;
      }
      float ss = 0.f;
      #pragma unroll
      for (int q = 0; q < 4; ++q)
        if (vb + q < VD) ss += __expf(lg[q] - m);
      #pragma unroll
      for (int msk = 16; msk; msk >>= 1) {
        float om = __shfl_xor(m, msk, 64);
        float os = __shfl_xor(ss, msk, 64);
        int oa = __shfl_xor(am, msk, 64);
        combine3(m, ss, am, om, os, oa);
      }
      if (tx == 0) {
        size_t pb = (size_t)(t0 + j) * NVT + vt;
        __hip_atomic_store(&C.pmax[pb], m, __ATOMIC_RELAXED, __HIP_MEMORY_SCOPE_AGENT);
        __hip_atomic_store(&C.psum[pb], ss, __ATOMIC_RELAXED, __HIP_MEMORY_SCOPE_AGENT);
        __hip_atomic_store(&C.parg[pb], am, __ATOMIC_RELAXED, __HIP_MEMORY_SCOPE_AGENT);
      }
    }
  }
}

__device__ __forceinline__ void merge_row65(const Ctx& C, int row, int lane,
                                            float& m, float& s, int& am) {
  size_t b = (size_t)row * NVT;
  m = ld_coh(C.pmax + b + lane);
  s = ld_coh(C.psum + b + lane);
  am = __hip_atomic_load(&C.parg[b + lane], __ATOMIC_RELAXED, __HIP_MEMORY_SCOPE_AGENT);
  if (lane == 0) {
    float om = ld_coh(C.pmax + b + 64);
    float os = ld_coh(C.psum + b + 64);
    int oa = __hip_atomic_load(&C.parg[b + 64], __ATOMIC_RELAXED, __HIP_MEMORY_SCOPE_AGENT);
    combine3(m, s, am, om, os, oa);
  }
  #pragma unroll
  for (int msk = 32; msk; msk >>= 1) {
    float om = __shfl_xor(m, msk, 64);
    float os = __shfl_xor(s, msk, 64);
    int oa = __shfl_xor(am, msk, 64);
    combine3(m, s, am, om, os, oa);
  }
}

__global__ __launch_bounds__(NTHR) void decode_kernel_f32(
    const float* enc, const float* emb, const float* Wih, const float* Whh,
    const float* bl, const float* Wpred, const float* bp, const float* Wjoin,
    const float* bj, const int* phon, float* out, float* wsf) {
  extern __shared__ float sm[];
  Ctx C;
  C.enc = enc; C.emb = emb; C.Wih = Wih; C.Whh = Whh; C.bl = bl;
  C.Wpred = Wpred; C.bp = bp; C.Wjoin = Wjoin; C.bj = bj; C.phon = phon;
  C.flags = (unsigned*)wsf;
  C.hx = (unsigned long long*)(wsf + L_HX);
  C.hhist = wsf + L_HHIST;
  C.preds = wsf + L_PREDS;
  C.pmax = wsf + F_PMAX;
  C.psum = wsf + F_PSUM;
  C.parg = (int*)(wsf + F_PARG);
  C.lse = wsf + F_LSE;
  C.out_align = out;
  C.out_pred  = out + (size_t)TT * VD;
  C.out_valid = out + (size_t)TT * VD + TT;

  const int tid = threadIdx.x;
  const int wid = tid >> 6, lane = tid & 63;
  unsigned ep = 1;

  chain_all_legacy(C, sm);
  heavy_barrier(C.flags);
  preds_gemm_legacy(C, sm);
  heavy_barrier(C.flags);

  int t = 0, tp = 0;
  while (t < TT && tp < NPH) {
    int K = CHUNK;
    if (TT - t < K) K = TT - t;
    if (NPH - tp < K) K = NPH - tp;
    joiner_gemm_f32(C, sm, t, K, tp);
    light_barrier(C.flags, ep);
    int* amax_l = (int*)(sm + S_AMAX);
    for (int j = wid; j < K; j += 8) {
      float m, s; int am;
      merge_row65(C, t + j, lane, m, s, am);
      if (lane == 0) {
        amax_l[j] = am;
        C.lse[t + j] = m + logf(s);
      }
    }
    __syncthreads();
    int cand = K;
    if (tid < K && amax_l[tid] == BLANK) cand = tid;
    #pragma unroll
    for (int msk = 32; msk; msk >>= 1) cand = min(cand, __shfl_xor(cand, msk, 64));
    int* red = (int*)(sm + S_RED);
    if (lane == 0) red[wid] = cand;
    __syncthreads();
    if (tid == 0) {
      int mn = red[0];
      for (int w2 = 1; w2 < 8; ++w2) mn = min(mn, red[w2]);
      red[8] = mn;
    }
    __syncthreads();
    int jb = red[8];
    __syncthreads();
    int nacc = (jb < K) ? jb + 1 : K;
    int nadv = (jb < K) ? jb : K;
    if (blockIdx.x == 0) {
      int* tok_sm = (int*)(sm + S_TOK);
      for (int j = tid; j < nacc; j += NTHR) {
        C.out_pred[t + j] = (j == jb) ? (float)BLANK : (float)tok_sm[tp + j + 2];
        C.out_valid[t + j] = 1.f;
      }
    }
    t += nacc; tp += nadv;
    if (jb < K) heavy_barrier(C.flags);
  }
  if (t < TT) {
    int Kt = TT - t;
    joiner_gemm_f32(C, sm, t, Kt, -1);
    light_barrier(C.flags, ep);
    for (int i = blockIdx.x * 8 + wid; i < Kt; i += NWG * 8) {
      float m, s; int am;
      merge_row65(C, t + i, lane, m, s, am);
      if (lane == 0) C.lse[t + i] = m + logf(s);
    }
    const int gtid = blockIdx.x * NTHR + tid;
    for (int i = gtid; i < Kt; i += NWG * NTHR) {
      C.out_pred[t + i] = (float)BLANK;
      C.out_valid[t + i] = 0.f;
    }
  }
  heavy_barrier(C.flags);
  for (int row = blockIdx.x; row < TT; row += NWG) {
    float l = C.lse[row];
    float* p = C.out_align + (size_t)row * VD;
    for (int i = tid; i < VD; i += NTHR) p[i] -= l;
  }
}

// ======================= host =======================

extern "C" void kernel_launch(void* const* d_in, const int* in_sizes, int n_in,
                              void* d_out, int out_size, void* d_ws, size_t ws_size,
                              hipStream_t stream) {
  const float* enc   = (const float*)d_in[0];
  const float* emb   = (const float*)d_in[1];
  const float* Wih   = (const float*)d_in[2];
  const float* Whh   = (const float*)d_in[3];
  const float* bl    = (const float*)d_in[4];
  const float* Wpred = (const float*)d_in[5];
  const float* bp    = (const float*)d_in[6];
  const float* Wjoin = (const float*)d_in[7];
  const float* bj    = (const float*)d_in[8];
  const int*   phon  = (const int*)d_in[9];
  float* out = (float*)d_out;
  float* wsf = (float*)d_ws;

  // flags + tagged h-exchange must start clean every call
  hipMemsetAsync(d_ws, 0, MEMSET_BYTES, stream);

  if (ws_size >= NEED_MFMA) {
    hipFuncSetAttribute((const void*)chain_kernel,
                        hipFuncAttributeMaxDynamicSharedMemorySize, CHAIN_SMEM);
    hipFuncSetAttribute((const void*)joinspec_kernel,
                        hipFuncAttributeMaxDynamicSharedMemorySize, JOIN_SMEM);
    hipFuncSetAttribute((const void*)decode_coop,
                        hipFuncAttributeMaxDynamicSharedMemorySize, JOIN_SMEM);
    hipFuncSetAttribute((const void*)jointail_kernel,
                        hipFuncAttributeMaxDynamicSharedMemorySize, JOIN_SMEM);

    wconv_kernel<<<1024, 512, 0, stream>>>(Wjoin, wsf);
    gx_kernel<<<416, 512, GEMM_SMEM, stream>>>(Wih, emb, bl, phon, wsf);
    {
      const float* WhhA = Whh; float* wsfA = wsf;
      void* a2[] = { &WhhA, &wsfA };
      hipError_t e = hipLaunchCooperativeKernel((void*)chain_kernel, dim3(256), dim3(NTHR),
                                                a2, CHAIN_SMEM, stream);
      if (e != hipSuccess)
        chain_kernel<<<dim3(256), dim3(NTHR), CHAIN_SMEM, stream>>>(Whh, wsf);
    }
    preds_kernel<<<104, 512, GEMM_SMEM, stream>>>(Wpred, bp, wsf);
    xspec_kernel<<<1024, 256, 0, stream>>>(enc, wsf);
    joinspec_kernel<<<455, NTHR, JOIN_SMEM, stream>>>(bj, out, wsf);
    {
      const float* encA = enc; const float* bjA = bj; const int* phonA = phon;
      float* outA = out; float* wsfA = wsf;
      void* a3[] = { &encA, &bjA, &phonA, &outA, &wsfA };
      hipError_t e = hipLaunchCooperativeKernel((void*)decode_coop, dim3(NWG), dim3(NTHR),
                                                a3, JOIN_SMEM, stream);
      if (e != hipSuccess)
        decode_coop<<<dim3(NWG), dim3(NTHR), JOIN_SMEM, stream>>>(enc, bj, phon, out, wsf);
    }
    jointail_kernel<<<1664, NTHR, JOIN_SMEM, stream>>>(bj, out, wsf);
    mergetail_kernel<<<256, NTHR, 0, stream>>>(out, wsf);
    sub_kernel<<<2048, 256, 0, stream>>>(out, wsf);
  } else {
    hipFuncSetAttribute((const void*)decode_kernel_f32,
                        hipFuncAttributeMaxDynamicSharedMemorySize, SMEM_BYTES_F32);
    void* args[] = { &enc, &emb, &Wih, &Whh, &bl, &Wpred, &bp, &Wjoin, &bj, &phon, &out, &wsf };
    hipError_t e = hipLaunchCooperativeKernel((void*)decode_kernel_f32, dim3(NWG), dim3(NTHR),
                                              args, SMEM_BYTES_F32, stream);
    if (e != hipSuccess) {
      decode_kernel_f32<<<dim3(NWG), dim3(NTHR), SMEM_BYTES_F32, stream>>>(
          enc, emb, Wih, Whh, bl, Wpred, bp, Wjoin, bj, phon, out, wsf);
    }
  }
}